// Round 1
// baseline (3089.330 us; speedup 1.0000x reference)
//
#include <hip/hip_runtime.h>

#define DIM 64

// ---------------- degree / counts / dinv ----------------

__global__ __launch_bounds__(256) void k_deg(const int* __restrict__ dst,
                                             int* __restrict__ deg, int E) {
    int e = blockIdx.x * blockDim.x + threadIdx.x;
    if (e < E) atomicAdd(&deg[dst[e]], 1);
}

__global__ __launch_bounds__(256) void k_count(const int* __restrict__ batch,
                                               int* __restrict__ cnt, int N) {
    int v = blockIdx.x * blockDim.x + threadIdx.x;
    if (v < N) atomicAdd(&cnt[batch[v]], 1);
}

__global__ __launch_bounds__(256) void k_dinv(const int* __restrict__ deg,
                                              float* __restrict__ dinv, int N) {
    int v = blockIdx.x * blockDim.x + threadIdx.x;
    if (v < N) dinv[v] = rsqrtf((float)(deg[v] + 1));  // +1 = self-loop; deg>=1 always
}

// ---------------- skinny GEMM: Y[N,64] = (relu? relu(X) : X) @ W ----------------
// W row-major [64,64]: out[r][c] = sum_k X[r][k] * W[k][c]

__global__ __launch_bounds__(256) void k_gemm(const float* __restrict__ X,
                                              const float* __restrict__ W,
                                              float* __restrict__ Y, int N, int relu_in) {
    __shared__ float Ws[64 * 64];
    __shared__ float Xs[16 * 64];
    int tid = threadIdx.x;
#pragma unroll
    for (int i = 0; i < 16; ++i) Ws[tid + 256 * i] = W[tid + 256 * i];

    int row0 = blockIdx.x * 16;
    int r = tid >> 4, c4 = (tid & 15) << 2;
    {
        float4 v = make_float4(0.f, 0.f, 0.f, 0.f);
        if (row0 + r < N) v = *(const float4*)(X + (size_t)(row0 + r) * DIM + c4);
        if (relu_in) {
            v.x = fmaxf(v.x, 0.f); v.y = fmaxf(v.y, 0.f);
            v.z = fmaxf(v.z, 0.f); v.w = fmaxf(v.w, 0.f);
        }
        *(float4*)(Xs + r * DIM + c4) = v;
    }
    __syncthreads();

    float4 acc = make_float4(0.f, 0.f, 0.f, 0.f);
#pragma unroll
    for (int k = 0; k < 64; ++k) {
        float xk = Xs[r * DIM + k];
        float4 w = *(const float4*)(Ws + k * DIM + c4);
        acc.x += xk * w.x; acc.y += xk * w.y;
        acc.z += xk * w.z; acc.w += xk * w.w;
    }
    if (row0 + r < N) *(float4*)(Y + (size_t)(row0 + r) * DIM + c4) = acc;
}

// ---------------- agg init: self-loop + bias ----------------
// agg[v][d] = h[v][d] * dinv[v]^2 + b[d]

__global__ __launch_bounds__(256) void k_init(const float* __restrict__ h,
                                              const float* __restrict__ dinv,
                                              const float* __restrict__ b,
                                              float* __restrict__ agg, int N) {
    int tid = blockIdx.x * blockDim.x + threadIdx.x;
    int v = tid >> 4, d4 = (tid & 15) << 2;
    if (v >= N) return;
    float n = dinv[v]; n = n * n;
    float4 hv = *(const float4*)(h + (size_t)v * DIM + d4);
    float4 bv = *(const float4*)(b + d4);
    float4 o = make_float4(hv.x * n + bv.x, hv.y * n + bv.y,
                           hv.z * n + bv.z, hv.w * n + bv.w);
    *(float4*)(agg + (size_t)v * DIM + d4) = o;
}

// ---------------- edge scatter: agg[dst] += h[src] * dinv[src]*dinv[dst] ----------------
// 16 lanes per edge, float4 per lane (one wave = 4 edges, 256B coalesced gather each)

__global__ __launch_bounds__(256) void k_scatter(const float* __restrict__ h,
                                                 const int* __restrict__ src,
                                                 const int* __restrict__ dst,
                                                 const float* __restrict__ dinv,
                                                 float* __restrict__ agg, int E) {
    int tid = blockIdx.x * blockDim.x + threadIdx.x;
    int e = tid >> 4, d4 = (tid & 15) << 2;
    if (e >= E) return;
    int s = src[e], t = dst[e];
    float norm = dinv[s] * dinv[t];
    float4 hv = *(const float4*)(h + (size_t)s * DIM + d4);
    float* base = agg + (size_t)t * DIM + d4;
    atomicAdd(base + 0, hv.x * norm);
    atomicAdd(base + 1, hv.y * norm);
    atomicAdd(base + 2, hv.z * norm);
    atomicAdd(base + 3, hv.w * norm);
}

// ---------------- pooling: out[batch[v]] += relu(agg[v]); then divide by counts ----------------

__global__ __launch_bounds__(256) void k_pool(const float* __restrict__ agg,
                                              const int* __restrict__ batch,
                                              float* __restrict__ out, int N) {
    int tid = blockIdx.x * blockDim.x + threadIdx.x;
    int v = tid >> 4, d4 = (tid & 15) << 2;
    if (v >= N) return;
    int g = batch[v];
    float4 hv = *(const float4*)(agg + (size_t)v * DIM + d4);
    float* o = out + (size_t)g * DIM + d4;
    atomicAdd(o + 0, fmaxf(hv.x, 0.f));
    atomicAdd(o + 1, fmaxf(hv.y, 0.f));
    atomicAdd(o + 2, fmaxf(hv.z, 0.f));
    atomicAdd(o + 3, fmaxf(hv.w, 0.f));
}

__global__ __launch_bounds__(256) void k_div(float* __restrict__ out,
                                             const int* __restrict__ cnt, int total) {
    int i = blockIdx.x * blockDim.x + threadIdx.x;
    if (i < total) out[i] /= fmaxf((float)cnt[i >> 6], 1.0f);
}

// ---------------- launch ----------------

static inline int cdiv(int a, int b) { return (a + b - 1) / b; }

extern "C" void kernel_launch(void* const* d_in, const int* in_sizes, int n_in,
                              void* d_out, int out_size, void* d_ws, size_t ws_size,
                              hipStream_t stream) {
    const float* x   = (const float*)d_in[0];
    const float* W1  = (const float*)d_in[1];
    const float* b1  = (const float*)d_in[2];
    const float* W2  = (const float*)d_in[3];
    const float* b2  = (const float*)d_in[4];
    const int*   ei  = (const int*)d_in[5];   // [2, E] flattened
    const int*   bat = (const int*)d_in[6];   // [N]

    const int N = in_sizes[0] / DIM;
    const int E = in_sizes[5] / 2;
    const int G = out_size / DIM;
    const int* src = ei;
    const int* dst = ei + E;

    float* out = (float*)d_out;

    // workspace: bufA(N*64) | bufB(N*64) | dinv(N) | deg(N int) | cnt(G int)
    float* bufA = (float*)d_ws;
    float* bufB = bufA + (size_t)N * DIM;
    float* dinv = bufB + (size_t)N * DIM;
    int*   deg  = (int*)(dinv + N);
    int*   cnt  = deg + N;

    hipMemsetAsync(deg, 0, (size_t)N * sizeof(int), stream);
    hipMemsetAsync(cnt, 0, (size_t)G * sizeof(int), stream);
    hipMemsetAsync(d_out, 0, (size_t)out_size * sizeof(float), stream);

    k_deg<<<cdiv(E, 256), 256, 0, stream>>>(dst, deg, E);
    k_count<<<cdiv(N, 256), 256, 0, stream>>>(bat, cnt, N);
    k_dinv<<<cdiv(N, 256), 256, 0, stream>>>(deg, dinv, N);

    // layer 1: h1 = x @ W1 (bufA); agg1 (bufB) = selfloop+bias, then edge scatter
    k_gemm<<<cdiv(N, 16), 256, 0, stream>>>(x, W1, bufA, N, 0);
    k_init<<<cdiv(N * 16, 256), 256, 0, stream>>>(bufA, dinv, b1, bufB, N);
    k_scatter<<<cdiv(E * 16, 256), 256, 0, stream>>>(bufA, src, dst, dinv, bufB, E);

    // layer 2: h2 = relu(agg1) @ W2 (bufA); agg2 (bufB overwritten after gemm reads it)
    k_gemm<<<cdiv(N, 16), 256, 0, stream>>>(bufB, W2, bufA, N, 1);
    k_init<<<cdiv(N * 16, 256), 256, 0, stream>>>(bufA, dinv, b2, bufB, N);
    k_scatter<<<cdiv(E * 16, 256), 256, 0, stream>>>(bufA, src, dst, dinv, bufB, E);

    // pool: out[g] = sum relu(agg2[v]) / count[g]
    k_pool<<<cdiv(N * 16, 256), 256, 0, stream>>>(bufB, bat, out, N);
    k_div<<<cdiv(out_size, 256), 256, 0, stream>>>(out, cnt, out_size);
}

// Round 2
// 664.988 us; speedup vs baseline: 4.6457x; 4.6457x over previous
//
#include <hip/hip_runtime.h>

#define DIM 64

// ---------------- degree / counts / dinv ----------------

__global__ __launch_bounds__(256) void k_deg(const int* __restrict__ dst,
                                             int* __restrict__ deg, int E) {
    int e = blockIdx.x * blockDim.x + threadIdx.x;
    if (e < E) atomicAdd(&deg[dst[e]], 1);
}

__global__ __launch_bounds__(256) void k_count(const int* __restrict__ batch,
                                               int* __restrict__ cnt, int N) {
    int v = blockIdx.x * blockDim.x + threadIdx.x;
    if (v < N) atomicAdd(&cnt[batch[v]], 1);
}

__global__ __launch_bounds__(256) void k_dinv(const int* __restrict__ deg,
                                              float* __restrict__ dinv, int N) {
    int v = blockIdx.x * blockDim.x + threadIdx.x;
    if (v < N) dinv[v] = rsqrtf((float)(deg[v] + 1));  // +1 = self-loop
}

// ---------------- exclusive scan over deg[N] -> off[N+1] (3-kernel) ----------------

__global__ __launch_bounds__(256) void k_scan1(const int* __restrict__ deg,
                                               int* __restrict__ off,
                                               int* __restrict__ bsum, int N) {
    __shared__ int s[256];
    int tid = threadIdx.x;
    int i = blockIdx.x * 256 + tid;
    int v = (i < N) ? deg[i] : 0;
    s[tid] = v;
    __syncthreads();
#pragma unroll
    for (int d = 1; d < 256; d <<= 1) {
        int t = (tid >= d) ? s[tid - d] : 0;
        __syncthreads();
        s[tid] += t;
        __syncthreads();
    }
    if (i < N) off[i] = s[tid] - v;              // exclusive within block
    if (tid == 255) bsum[blockIdx.x] = s[255];   // block total
}

__global__ __launch_bounds__(1024) void k_scan2(int* __restrict__ bsum, int nb) {
    __shared__ int s[1024];
    int tid = threadIdx.x;
    int v = (tid < nb) ? bsum[tid] : 0;
    s[tid] = v;
    __syncthreads();
#pragma unroll
    for (int d = 1; d < 1024; d <<= 1) {
        int t = (tid >= d) ? s[tid - d] : 0;
        __syncthreads();
        s[tid] += t;
        __syncthreads();
    }
    if (tid < nb) bsum[tid] = s[tid] - v;        // exclusive block offsets
}

__global__ __launch_bounds__(256) void k_scan3(int* __restrict__ off,
                                               const int* __restrict__ bsum,
                                               int N, int total) {
    int i = blockIdx.x * 256 + threadIdx.x;
    if (i < N) off[i] += bsum[blockIdx.x];
    if (i == N - 1) off[N] = total;
}

// single-block exclusive scan for graph counts (G <= 1024)
__global__ __launch_bounds__(1024) void k_scanG(const int* __restrict__ cnt,
                                                int* __restrict__ goff, int G, int N) {
    __shared__ int s[1024];
    int tid = threadIdx.x;
    int v = (tid < G) ? cnt[tid] : 0;
    s[tid] = v;
    __syncthreads();
#pragma unroll
    for (int d = 1; d < 1024; d <<= 1) {
        int t = (tid >= d) ? s[tid - d] : 0;
        __syncthreads();
        s[tid] += t;
        __syncthreads();
    }
    if (tid < G) goff[tid] = s[tid] - v;
    if (tid == 0) goff[G] = N;
}

// ---------------- CSR fill: csr_src[slot] = src[e], slots grouped by dst ----------------

__global__ __launch_bounds__(256) void k_fill(const int* __restrict__ src,
                                              const int* __restrict__ dst,
                                              const int* __restrict__ off,
                                              int* __restrict__ cur,
                                              int* __restrict__ csr_src, int E) {
    int e = blockIdx.x * blockDim.x + threadIdx.x;
    if (e >= E) return;
    int t = dst[e];
    int slot = off[t] + atomicAdd(&cur[t], 1);
    csr_src[slot] = src[e];
}

// ---------------- skinny GEMM: Y[N,64] = (relu? relu(X) : X) @ W ----------------

__global__ __launch_bounds__(256) void k_gemm(const float* __restrict__ X,
                                              const float* __restrict__ W,
                                              float* __restrict__ Y, int N, int relu_in) {
    __shared__ float Ws[64 * 64];
    __shared__ float Xs[16 * 64];
    int tid = threadIdx.x;
#pragma unroll
    for (int i = 0; i < 16; ++i) Ws[tid + 256 * i] = W[tid + 256 * i];

    int row0 = blockIdx.x * 16;
    int r = tid >> 4, c4 = (tid & 15) << 2;
    {
        float4 v = make_float4(0.f, 0.f, 0.f, 0.f);
        if (row0 + r < N) v = *(const float4*)(X + (size_t)(row0 + r) * DIM + c4);
        if (relu_in) {
            v.x = fmaxf(v.x, 0.f); v.y = fmaxf(v.y, 0.f);
            v.z = fmaxf(v.z, 0.f); v.w = fmaxf(v.w, 0.f);
        }
        *(float4*)(Xs + r * DIM + c4) = v;
    }
    __syncthreads();

    float4 acc = make_float4(0.f, 0.f, 0.f, 0.f);
#pragma unroll
    for (int k = 0; k < 64; ++k) {
        float xk = Xs[r * DIM + k];
        float4 w = *(const float4*)(Ws + k * DIM + c4);
        acc.x += xk * w.x; acc.y += xk * w.y;
        acc.z += xk * w.z; acc.w += xk * w.w;
    }
    if (row0 + r < N) *(float4*)(Y + (size_t)(row0 + r) * DIM + c4) = acc;
}

// ---------------- gather: agg[v] = h[v]*dinv[v]^2 + b + sum_{s in nbr(v)} h[s]*dinv[s]*dinv[v] ----------------
// one 64-lane wave per dst node; lane owns one dim; 256B coalesced row reads

__global__ __launch_bounds__(256) void k_gather(const float* __restrict__ h,
                                                const int* __restrict__ csr_src,
                                                const int* __restrict__ off,
                                                const float* __restrict__ dinv,
                                                const float* __restrict__ b,
                                                float* __restrict__ agg, int N) {
    int v = (blockIdx.x * 256 + threadIdx.x) >> 6;   // one wave per node
    int lane = threadIdx.x & 63;
    if (v >= N) return;
    float dv = dinv[v];
    float acc = h[(size_t)v * DIM + lane] * dv * dv + b[lane];
    int k1 = off[v + 1];
    for (int k = off[v]; k < k1; ++k) {
        int s = csr_src[k];                          // broadcast load
        float nm = dinv[s] * dv;
        acc += h[(size_t)s * DIM + lane] * nm;       // 256B coalesced per wave
    }
    agg[(size_t)v * DIM + lane] = acc;
}

// ---------------- pool: out[g] = sum_{v in graph g} relu(agg[v]) / count ----------------
// batch sorted -> graph g owns nodes [goff[g], goff[g+1]); one wave per graph

__global__ __launch_bounds__(256) void k_pool(const float* __restrict__ agg,
                                              const int* __restrict__ goff,
                                              float* __restrict__ out, int G) {
    int g = blockIdx.x * 4 + (threadIdx.x >> 6);
    if (g >= G) return;
    int lane = threadIdx.x & 63;
    int q = lane >> 4, d4 = (lane & 15) << 2;
    int n0 = goff[g], n1 = goff[g + 1];
    float4 acc = make_float4(0.f, 0.f, 0.f, 0.f);
    for (int i = n0 + q; i < n1; i += 4) {
        float4 hv = *(const float4*)(agg + (size_t)i * DIM + d4);
        acc.x += fmaxf(hv.x, 0.f); acc.y += fmaxf(hv.y, 0.f);
        acc.z += fmaxf(hv.z, 0.f); acc.w += fmaxf(hv.w, 0.f);
    }
    // reduce the 4 quarter-wave partials (lanes l, l+16, l+32, l+48)
    acc.x += __shfl_down(acc.x, 32); acc.y += __shfl_down(acc.y, 32);
    acc.z += __shfl_down(acc.z, 32); acc.w += __shfl_down(acc.w, 32);
    acc.x += __shfl_down(acc.x, 16); acc.y += __shfl_down(acc.y, 16);
    acc.z += __shfl_down(acc.z, 16); acc.w += __shfl_down(acc.w, 16);
    if (q == 0) {
        float inv = 1.0f / fmaxf((float)(n1 - n0), 1.0f);
        float4 o = make_float4(acc.x * inv, acc.y * inv, acc.z * inv, acc.w * inv);
        *(float4*)(out + (size_t)g * DIM + d4) = o;
    }
}

// ---------------- launch ----------------

static inline int cdiv(int a, int b) { return (a + b - 1) / b; }

extern "C" void kernel_launch(void* const* d_in, const int* in_sizes, int n_in,
                              void* d_out, int out_size, void* d_ws, size_t ws_size,
                              hipStream_t stream) {
    const float* x   = (const float*)d_in[0];
    const float* W1  = (const float*)d_in[1];
    const float* b1  = (const float*)d_in[2];
    const float* W2  = (const float*)d_in[3];
    const float* b2  = (const float*)d_in[4];
    const int*   ei  = (const int*)d_in[5];   // [2, E] flattened
    const int*   bat = (const int*)d_in[6];   // [N]

    const int N = in_sizes[0] / DIM;
    const int E = in_sizes[5] / 2;
    const int G = out_size / DIM;
    const int* src = ei;
    const int* dst = ei + E;
    float* out = (float*)d_out;

    // workspace layout (floats/ints are 4B; float4 alignment preserved)
    float* bufA = (float*)d_ws;                    // N*64 f
    float* bufB = bufA + (size_t)N * DIM;          // N*64 f
    float* dinv = bufB + (size_t)N * DIM;          // N f
    int*   deg  = (int*)(dinv + N);                // N i
    int*   off  = deg + N;                         // N+1 i
    int*   cur  = off + (N + 1);                   // N i
    int*   cnt  = cur + N;                         // G i
    int*   goff = cnt + G;                         // G+1 i
    int*   bsum = goff + (G + 1);                  // up to 1024 i
    int*   csr  = bsum + 1024;                     // E i

    hipMemsetAsync(deg, 0, (size_t)N * sizeof(int), stream);
    hipMemsetAsync(cur, 0, (size_t)N * sizeof(int), stream);
    hipMemsetAsync(cnt, 0, (size_t)G * sizeof(int), stream);

    k_deg<<<cdiv(E, 256), 256, 0, stream>>>(dst, deg, E);
    k_count<<<cdiv(N, 256), 256, 0, stream>>>(bat, cnt, N);
    k_dinv<<<cdiv(N, 256), 256, 0, stream>>>(deg, dinv, N);

    int nb = cdiv(N, 256);
    k_scan1<<<nb, 256, 0, stream>>>(deg, off, bsum, N);
    k_scan2<<<1, 1024, 0, stream>>>(bsum, nb);
    k_scan3<<<nb, 256, 0, stream>>>(off, bsum, N, E);
    k_scanG<<<1, 1024, 0, stream>>>(cnt, goff, G, N);

    k_fill<<<cdiv(E, 256), 256, 0, stream>>>(src, dst, off, cur, csr, E);

    // layer 1: h1 = x @ W1 (bufA); agg1 = gather (bufB)
    k_gemm<<<cdiv(N, 16), 256, 0, stream>>>(x, W1, bufA, N, 0);
    k_gather<<<cdiv(N, 4), 256, 0, stream>>>(bufA, csr, off, dinv, b1, bufB, N);

    // layer 2: h2 = relu(agg1) @ W2 (bufA); agg2 = gather (bufB)
    k_gemm<<<cdiv(N, 16), 256, 0, stream>>>(bufB, W2, bufA, N, 1);
    k_gather<<<cdiv(N, 4), 256, 0, stream>>>(bufA, csr, off, dinv, b2, bufB, N);

    // pool: out[g] = mean relu(agg2[v]) over graph g
    k_pool<<<cdiv(G, 4), 256, 0, stream>>>(bufB, goff, out, G);
}

// Round 4
// 468.662 us; speedup vs baseline: 6.5918x; 1.4189x over previous
//
#include <hip/hip_runtime.h>

#define DIM 64

// ---------------- degree (by dst) + per-graph counts, fused ----------------

__global__ __launch_bounds__(256) void k_degcnt(const int* __restrict__ dst,
                                                const int* __restrict__ batch,
                                                int* __restrict__ deg,
                                                int* __restrict__ cnt, int E, int N) {
    int i = blockIdx.x * blockDim.x + threadIdx.x;
    if (i < E) atomicAdd(&deg[dst[i]], 1);
    if (i < N) atomicAdd(&cnt[batch[i]], 1);
}

// ---------------- exclusive scan over deg[N] -> off[N+1]; also dinv ----------------

__global__ __launch_bounds__(256) void k_scan1(const int* __restrict__ deg,
                                               int* __restrict__ off,
                                               int* __restrict__ bsum,
                                               float* __restrict__ dinv, int N) {
    __shared__ int s[256];
    int tid = threadIdx.x;
    int i = blockIdx.x * 256 + tid;
    int v = (i < N) ? deg[i] : 0;
    if (i < N) dinv[i] = rsqrtf((float)(v + 1));  // +1 self-loop
    s[tid] = v;
    __syncthreads();
#pragma unroll
    for (int d = 1; d < 256; d <<= 1) {
        int t = (tid >= d) ? s[tid - d] : 0;
        __syncthreads();
        s[tid] += t;
        __syncthreads();
    }
    if (i < N) off[i] = s[tid] - v;
    if (tid == 255) bsum[blockIdx.x] = s[255];
}

__global__ __launch_bounds__(1024) void k_scan2(int* __restrict__ bsum, int nb) {
    __shared__ int s[1024];
    int tid = threadIdx.x;
    int v = (tid < nb) ? bsum[tid] : 0;
    s[tid] = v;
    __syncthreads();
#pragma unroll
    for (int d = 1; d < 1024; d <<= 1) {
        int t = (tid >= d) ? s[tid - d] : 0;
        __syncthreads();
        s[tid] += t;
        __syncthreads();
    }
    if (tid < nb) bsum[tid] = s[tid] - v;
}

__global__ __launch_bounds__(256) void k_scan3(int* __restrict__ off,
                                               const int* __restrict__ bsum,
                                               int N, int total) {
    int i = blockIdx.x * 256 + threadIdx.x;
    if (i < N) off[i] += bsum[blockIdx.x];
    if (i == N - 1) off[N] = total;
}

__global__ __launch_bounds__(1024) void k_scanG(const int* __restrict__ cnt,
                                                int* __restrict__ goff, int G, int N) {
    __shared__ int s[1024];
    int tid = threadIdx.x;
    int v = (tid < G) ? cnt[tid] : 0;
    s[tid] = v;
    __syncthreads();
#pragma unroll
    for (int d = 1; d < 1024; d <<= 1) {
        int t = (tid >= d) ? s[tid - d] : 0;
        __syncthreads();
        s[tid] += t;
        __syncthreads();
    }
    if (tid < G) goff[tid] = s[tid] - v;
    if (tid == 0) goff[G] = N;
}

// ---------------- CSR fill ----------------

__global__ __launch_bounds__(256) void k_fill(const int* __restrict__ src,
                                              const int* __restrict__ dst,
                                              const int* __restrict__ off,
                                              int* __restrict__ cur,
                                              int* __restrict__ csr_src, int E) {
    int e = blockIdx.x * blockDim.x + threadIdx.x;
    if (e >= E) return;
    int t = dst[e];
    int slot = off[t] + atomicAdd(&cur[t], 1);
    csr_src[slot] = src[e];
}

// ---------------- skinny GEMM: Y[N,64] = (relu? relu(X) : X) @ W ----------------

__global__ __launch_bounds__(256) void k_gemm(const float* __restrict__ X,
                                              const float* __restrict__ W,
                                              float* __restrict__ Y, int N, int relu_in) {
    __shared__ float Ws[64 * 64];
    __shared__ float Xs[16 * 64];
    int tid = threadIdx.x;
#pragma unroll
    for (int i = 0; i < 16; ++i) Ws[tid + 256 * i] = W[tid + 256 * i];

    int row0 = blockIdx.x * 16;
    int r = tid >> 4, c4 = (tid & 15) << 2;
    {
        float4 v = make_float4(0.f, 0.f, 0.f, 0.f);
        if (row0 + r < N) v = *(const float4*)(X + (size_t)(row0 + r) * DIM + c4);
        if (relu_in) {
            v.x = fmaxf(v.x, 0.f); v.y = fmaxf(v.y, 0.f);
            v.z = fmaxf(v.z, 0.f); v.w = fmaxf(v.w, 0.f);
        }
        *(float4*)(Xs + r * DIM + c4) = v;
    }
    __syncthreads();

    float4 acc = make_float4(0.f, 0.f, 0.f, 0.f);
#pragma unroll
    for (int k = 0; k < 64; ++k) {
        float xk = Xs[r * DIM + k];
        float4 w = *(const float4*)(Ws + k * DIM + c4);
        acc.x += xk * w.x; acc.y += xk * w.y;
        acc.z += xk * w.z; acc.w += xk * w.w;
    }
    if (row0 + r < N) *(float4*)(Y + (size_t)(row0 + r) * DIM + c4) = acc;
}

// ---------------- gather v2: wave per node, staged indices + 8-wide MLP ----------------
// agg[v] = h[v]*dinv[v]^2 + b + sum_{s in nbr(v)} h[s]*dinv[s]*dinv[v]

__global__ __launch_bounds__(256) void k_gather(const float* __restrict__ h,
                                                const int* __restrict__ csr_src,
                                                const int* __restrict__ off,
                                                const float* __restrict__ dinv,
                                                const float* __restrict__ b,
                                                float* __restrict__ agg, int N) {
    int v = (blockIdx.x * 256 + threadIdx.x) >> 6;
    int lane = threadIdx.x & 63;
    if (v >= N) return;
    float dv = dinv[v];
    float acc = h[((size_t)v << 6) + lane] * dv * dv + b[lane];
    int k0 = off[v], k1 = off[v + 1];

    for (int kb = k0; kb < k1; kb += 64) {
        int m = k1 - kb; if (m > 64) m = 64;
        int idx = 0; float wgt = 0.f;
        if (lane < m) {
            idx = csr_src[kb + lane];          // coalesced, one load per 64 edges
            wgt = dinv[idx] * dv;              // L2-resident gather
        }
        int mm = (m + 7) & ~7;
        for (int j = 0; j < mm; j += 8) {      // 8 independent row loads in flight
            int s0 = __shfl(idx, j + 0), s1 = __shfl(idx, j + 1);
            int s2 = __shfl(idx, j + 2), s3 = __shfl(idx, j + 3);
            int s4 = __shfl(idx, j + 4), s5 = __shfl(idx, j + 5);
            int s6 = __shfl(idx, j + 6), s7 = __shfl(idx, j + 7);
            float w0 = __shfl(wgt, j + 0), w1 = __shfl(wgt, j + 1);
            float w2 = __shfl(wgt, j + 2), w3 = __shfl(wgt, j + 3);
            float w4 = __shfl(wgt, j + 4), w5 = __shfl(wgt, j + 5);
            float w6 = __shfl(wgt, j + 6), w7 = __shfl(wgt, j + 7);
            float v0 = h[((size_t)s0 << 6) + lane];
            float v1 = h[((size_t)s1 << 6) + lane];
            float v2 = h[((size_t)s2 << 6) + lane];
            float v3 = h[((size_t)s3 << 6) + lane];
            float v4 = h[((size_t)s4 << 6) + lane];
            float v5 = h[((size_t)s5 << 6) + lane];
            float v6 = h[((size_t)s6 << 6) + lane];
            float v7 = h[((size_t)s7 << 6) + lane];
            acc += v0 * w0; acc += v1 * w1; acc += v2 * w2; acc += v3 * w3;
            acc += v4 * w4; acc += v5 * w5; acc += v6 * w6; acc += v7 * w7;
        }
    }
    agg[((size_t)v << 6) + lane] = acc;
}

// ---------------- pool ----------------

__global__ __launch_bounds__(256) void k_pool(const float* __restrict__ agg,
                                              const int* __restrict__ goff,
                                              float* __restrict__ out, int G) {
    int g = blockIdx.x * 4 + (threadIdx.x >> 6);
    if (g >= G) return;
    int lane = threadIdx.x & 63;
    int q = lane >> 4, d4 = (lane & 15) << 2;
    int n0 = goff[g], n1 = goff[g + 1];
    float4 acc = make_float4(0.f, 0.f, 0.f, 0.f);
    for (int i = n0 + q; i < n1; i += 4) {
        float4 hv = *(const float4*)(agg + ((size_t)i << 6) + d4);
        acc.x += fmaxf(hv.x, 0.f); acc.y += fmaxf(hv.y, 0.f);
        acc.z += fmaxf(hv.z, 0.f); acc.w += fmaxf(hv.w, 0.f);
    }
    acc.x += __shfl_down(acc.x, 32); acc.y += __shfl_down(acc.y, 32);
    acc.z += __shfl_down(acc.z, 32); acc.w += __shfl_down(acc.w, 32);
    acc.x += __shfl_down(acc.x, 16); acc.y += __shfl_down(acc.y, 16);
    acc.z += __shfl_down(acc.z, 16); acc.w += __shfl_down(acc.w, 16);
    if (q == 0) {
        float inv = 1.0f / fmaxf((float)(n1 - n0), 1.0f);
        *(float4*)(out + ((size_t)g << 6) + d4) =
            make_float4(acc.x * inv, acc.y * inv, acc.z * inv, acc.w * inv);
    }
}

// ---------------- launch ----------------

static inline int cdiv(int a, int b) { return (a + b - 1) / b; }

extern "C" void kernel_launch(void* const* d_in, const int* in_sizes, int n_in,
                              void* d_out, int out_size, void* d_ws, size_t ws_size,
                              hipStream_t stream) {
    const float* x   = (const float*)d_in[0];
    const float* W1  = (const float*)d_in[1];
    const float* b1  = (const float*)d_in[2];
    const float* W2  = (const float*)d_in[3];
    const float* b2  = (const float*)d_in[4];
    const int*   ei  = (const int*)d_in[5];
    const int*   bat = (const int*)d_in[6];

    const int N = in_sizes[0] / DIM;
    const int E = in_sizes[5] / 2;
    const int G = out_size / DIM;
    const int* src = ei;
    const int* dst = ei + E;
    float* out = (float*)d_out;

    // workspace: bufA | bufB | dinv | [deg cur cnt] (contiguous for one memset) | off | goff | bsum | csr
    float* bufA = (float*)d_ws;                    // N*64 f
    float* bufB = bufA + (size_t)N * DIM;          // N*64 f
    float* dinv = bufB + (size_t)N * DIM;          // N f
    int*   deg  = (int*)(dinv + N);                // N i  \ one
    int*   cur  = deg + N;                         // N i   } memset
    int*   cnt  = cur + N;                         // G i  /
    int*   off  = cnt + G;                         // N+1 i
    int*   goff = off + (N + 1);                   // G+1 i
    int*   bsum = goff + (G + 1);                  // 1024 i
    int*   csr  = bsum + 1024;                     // E i

    (void)hipMemsetAsync(deg, 0, (size_t)(2 * N + G) * sizeof(int), stream);

    k_degcnt<<<cdiv(E, 256), 256, 0, stream>>>(dst, bat, deg, cnt, E, N);

    int nb = cdiv(N, 256);
    k_scan1<<<nb, 256, 0, stream>>>(deg, off, bsum, dinv, N);
    k_scan2<<<1, 1024, 0, stream>>>(bsum, nb);
    k_scan3<<<nb, 256, 0, stream>>>(off, bsum, N, E);
    k_scanG<<<1, 1024, 0, stream>>>(cnt, goff, G, N);

    k_fill<<<cdiv(E, 256), 256, 0, stream>>>(src, dst, off, cur, csr, E);

    k_gemm<<<cdiv(N, 16), 256, 0, stream>>>(x, W1, bufA, N, 0);
    k_gather<<<cdiv(N, 4), 256, 0, stream>>>(bufA, csr, off, dinv, b1, bufB, N);

    k_gemm<<<cdiv(N, 16), 256, 0, stream>>>(bufB, W2, bufA, N, 1);
    k_gather<<<cdiv(N, 4), 256, 0, stream>>>(bufA, csr, off, dinv, b2, bufB, N);

    k_pool<<<cdiv(G, 4), 256, 0, stream>>>(bufB, goff, out, G);
}

// Round 5
// 414.636 us; speedup vs baseline: 7.4507x; 1.1303x over previous
//
#include <hip/hip_runtime.h>

#define DIM 64
#define FILL_EPB 2048

// ---------------- degree (by dst) + slot assignment + per-graph counts ----------------

__global__ __launch_bounds__(256) void k_degcnt(const int* __restrict__ dst,
                                                const int* __restrict__ batch,
                                                int* __restrict__ deg,
                                                int* __restrict__ cnt,
                                                int* __restrict__ eslot, int E, int N) {
    int i = blockIdx.x * blockDim.x + threadIdx.x;
    if (i < E) eslot[i] = atomicAdd(&deg[dst[i]], 1);  // unique slot within dst bucket
    if (i < N) atomicAdd(&cnt[batch[i]], 1);
}

// ---------------- exclusive scan over deg[N] -> off[N+1]; also dinv ----------------

__global__ __launch_bounds__(256) void k_scan1(const int* __restrict__ deg,
                                               int* __restrict__ off,
                                               int* __restrict__ bsum,
                                               float* __restrict__ dinv, int N) {
    __shared__ int s[256];
    int tid = threadIdx.x;
    int i = blockIdx.x * 256 + tid;
    int v = (i < N) ? deg[i] : 0;
    if (i < N) dinv[i] = rsqrtf((float)(v + 1));  // +1 self-loop
    s[tid] = v;
    __syncthreads();
#pragma unroll
    for (int d = 1; d < 256; d <<= 1) {
        int t = (tid >= d) ? s[tid - d] : 0;
        __syncthreads();
        s[tid] += t;
        __syncthreads();
    }
    if (i < N) off[i] = s[tid] - v;
    if (tid == 255) bsum[blockIdx.x] = s[255];
}

__global__ __launch_bounds__(1024) void k_scan2(int* __restrict__ bsum, int nb) {
    __shared__ int s[1024];
    int tid = threadIdx.x;
    int v = (tid < nb) ? bsum[tid] : 0;
    s[tid] = v;
    __syncthreads();
#pragma unroll
    for (int d = 1; d < 1024; d <<= 1) {
        int t = (tid >= d) ? s[tid - d] : 0;
        __syncthreads();
        s[tid] += t;
        __syncthreads();
    }
    if (tid < nb) bsum[tid] = s[tid] - v;
}

__global__ __launch_bounds__(256) void k_scan3(int* __restrict__ off,
                                               const int* __restrict__ bsum,
                                               int N, int total) {
    int i = blockIdx.x * 256 + threadIdx.x;
    if (i < N) off[i] += bsum[blockIdx.x];
    if (i == N - 1) off[N] = total;
}

__global__ __launch_bounds__(1024) void k_scanG(const int* __restrict__ cnt,
                                                int* __restrict__ goff, int G, int N) {
    __shared__ int s[1024];
    int tid = threadIdx.x;
    int v = (tid < G) ? cnt[tid] : 0;
    s[tid] = v;
    __syncthreads();
#pragma unroll
    for (int d = 1; d < 1024; d <<= 1) {
        int t = (tid >= d) ? s[tid - d] : 0;
        __syncthreads();
        s[tid] += t;
        __syncthreads();
    }
    if (tid < G) goff[tid] = s[tid] - v;
    if (tid == 0) goff[G] = N;
}

// ---------------- CSR fill, dst-range partitioned for XCD write locality ----------------
// blockIdx&7 = dst-range id (round-robin -> same XCD caches one ~0.8MB csr slice);
// no atomics (eslot precomputed); csr lines fill completely before writeback.

__global__ __launch_bounds__(256) void k_fill(const int* __restrict__ src,
                                              const int* __restrict__ dst,
                                              const int* __restrict__ off,
                                              const int* __restrict__ eslot,
                                              int* __restrict__ csr, int E, int chunk) {
    int r = blockIdx.x & 7;
    int s = blockIdx.x >> 3;
    int rlo = r * chunk, rhi = rlo + chunk;
    int e0 = s * FILL_EPB;
    int e1 = e0 + FILL_EPB; if (e1 > E) e1 = E;
    for (int e = e0 + (int)threadIdx.x; e < e1; e += 256) {
        int t = dst[e];
        if (t >= rlo && t < rhi) {
            csr[off[t] + eslot[e]] = src[e];
        }
    }
}

// ---------------- skinny GEMM: Y[N,64] = (relu? relu(X) : X) @ W ----------------

__global__ __launch_bounds__(256) void k_gemm(const float* __restrict__ X,
                                              const float* __restrict__ W,
                                              float* __restrict__ Y, int N, int relu_in) {
    __shared__ float Ws[64 * 64];
    __shared__ float Xs[16 * 64];
    int tid = threadIdx.x;
#pragma unroll
    for (int i = 0; i < 16; ++i) Ws[tid + 256 * i] = W[tid + 256 * i];

    int row0 = blockIdx.x * 16;
    int r = tid >> 4, c4 = (tid & 15) << 2;
    {
        float4 v = make_float4(0.f, 0.f, 0.f, 0.f);
        if (row0 + r < N) v = *(const float4*)(X + (size_t)(row0 + r) * DIM + c4);
        if (relu_in) {
            v.x = fmaxf(v.x, 0.f); v.y = fmaxf(v.y, 0.f);
            v.z = fmaxf(v.z, 0.f); v.w = fmaxf(v.w, 0.f);
        }
        *(float4*)(Xs + r * DIM + c4) = v;
    }
    __syncthreads();

    float4 acc = make_float4(0.f, 0.f, 0.f, 0.f);
#pragma unroll
    for (int k = 0; k < 64; ++k) {
        float xk = Xs[r * DIM + k];
        float4 w = *(const float4*)(Ws + k * DIM + c4);
        acc.x += xk * w.x; acc.y += xk * w.y;
        acc.z += xk * w.z; acc.w += xk * w.w;
    }
    if (row0 + r < N) *(float4*)(Y + (size_t)(row0 + r) * DIM + c4) = acc;
}

// ---------------- gather: wave per node, staged indices + 8-wide MLP ----------------

__global__ __launch_bounds__(256) void k_gather(const float* __restrict__ h,
                                                const int* __restrict__ csr_src,
                                                const int* __restrict__ off,
                                                const float* __restrict__ dinv,
                                                const float* __restrict__ b,
                                                float* __restrict__ agg, int N) {
    int v = (blockIdx.x * 256 + threadIdx.x) >> 6;
    int lane = threadIdx.x & 63;
    if (v >= N) return;
    float dv = dinv[v];
    float acc = h[((size_t)v << 6) + lane] * dv * dv + b[lane];
    int k0 = off[v], k1 = off[v + 1];

    for (int kb = k0; kb < k1; kb += 64) {
        int m = k1 - kb; if (m > 64) m = 64;
        int idx = 0; float wgt = 0.f;
        if (lane < m) {
            idx = csr_src[kb + lane];
            wgt = dinv[idx] * dv;
        }
        int mm = (m + 7) & ~7;
        for (int j = 0; j < mm; j += 8) {
            int s0 = __shfl(idx, j + 0), s1 = __shfl(idx, j + 1);
            int s2 = __shfl(idx, j + 2), s3 = __shfl(idx, j + 3);
            int s4 = __shfl(idx, j + 4), s5 = __shfl(idx, j + 5);
            int s6 = __shfl(idx, j + 6), s7 = __shfl(idx, j + 7);
            float w0 = __shfl(wgt, j + 0), w1 = __shfl(wgt, j + 1);
            float w2 = __shfl(wgt, j + 2), w3 = __shfl(wgt, j + 3);
            float w4 = __shfl(wgt, j + 4), w5 = __shfl(wgt, j + 5);
            float w6 = __shfl(wgt, j + 6), w7 = __shfl(wgt, j + 7);
            float v0 = h[((size_t)s0 << 6) + lane];
            float v1 = h[((size_t)s1 << 6) + lane];
            float v2 = h[((size_t)s2 << 6) + lane];
            float v3 = h[((size_t)s3 << 6) + lane];
            float v4 = h[((size_t)s4 << 6) + lane];
            float v5 = h[((size_t)s5 << 6) + lane];
            float v6 = h[((size_t)s6 << 6) + lane];
            float v7 = h[((size_t)s7 << 6) + lane];
            acc += v0 * w0; acc += v1 * w1; acc += v2 * w2; acc += v3 * w3;
            acc += v4 * w4; acc += v5 * w5; acc += v6 * w6; acc += v7 * w7;
        }
    }
    agg[((size_t)v << 6) + lane] = acc;
}

// ---------------- pool ----------------

__global__ __launch_bounds__(256) void k_pool(const float* __restrict__ agg,
                                              const int* __restrict__ goff,
                                              float* __restrict__ out, int G) {
    int g = blockIdx.x * 4 + (threadIdx.x >> 6);
    if (g >= G) return;
    int lane = threadIdx.x & 63;
    int q = lane >> 4, d4 = (lane & 15) << 2;
    int n0 = goff[g], n1 = goff[g + 1];
    float4 acc = make_float4(0.f, 0.f, 0.f, 0.f);
    for (int i = n0 + q; i < n1; i += 4) {
        float4 hv = *(const float4*)(agg + ((size_t)i << 6) + d4);
        acc.x += fmaxf(hv.x, 0.f); acc.y += fmaxf(hv.y, 0.f);
        acc.z += fmaxf(hv.z, 0.f); acc.w += fmaxf(hv.w, 0.f);
    }
    acc.x += __shfl_down(acc.x, 32); acc.y += __shfl_down(acc.y, 32);
    acc.z += __shfl_down(acc.z, 32); acc.w += __shfl_down(acc.w, 32);
    acc.x += __shfl_down(acc.x, 16); acc.y += __shfl_down(acc.y, 16);
    acc.z += __shfl_down(acc.z, 16); acc.w += __shfl_down(acc.w, 16);
    if (q == 0) {
        float inv = 1.0f / fmaxf((float)(n1 - n0), 1.0f);
        *(float4*)(out + ((size_t)g << 6) + d4) =
            make_float4(acc.x * inv, acc.y * inv, acc.z * inv, acc.w * inv);
    }
}

// ---------------- launch ----------------

static inline int cdiv(int a, int b) { return (a + b - 1) / b; }

extern "C" void kernel_launch(void* const* d_in, const int* in_sizes, int n_in,
                              void* d_out, int out_size, void* d_ws, size_t ws_size,
                              hipStream_t stream) {
    const float* x   = (const float*)d_in[0];
    const float* W1  = (const float*)d_in[1];
    const float* b1  = (const float*)d_in[2];
    const float* W2  = (const float*)d_in[3];
    const float* b2  = (const float*)d_in[4];
    const int*   ei  = (const int*)d_in[5];
    const int*   bat = (const int*)d_in[6];

    const int N = in_sizes[0] / DIM;
    const int E = in_sizes[5] / 2;
    const int G = out_size / DIM;
    const int* src = ei;
    const int* dst = ei + E;
    float* out = (float*)d_out;

    // workspace: bufA | bufB | dinv | [deg cnt] (one memset) | off | goff | bsum | eslot | csr
    float* bufA  = (float*)d_ws;                   // N*64 f
    float* bufB  = bufA + (size_t)N * DIM;         // N*64 f
    float* dinv  = bufB + (size_t)N * DIM;         // N f
    int*   deg   = (int*)(dinv + N);               // N i  \ one memset
    int*   cnt   = deg + N;                        // G i  /
    int*   off   = cnt + G;                        // N+1 i
    int*   goff  = off + (N + 1);                  // G+1 i
    int*   bsum  = goff + (G + 1);                 // 1024 i
    int*   eslot = bsum + 1024;                    // E i
    int*   csr   = eslot + E;                      // E i

    (void)hipMemsetAsync(deg, 0, (size_t)(N + G) * sizeof(int), stream);

    k_degcnt<<<cdiv(E, 256), 256, 0, stream>>>(dst, bat, deg, cnt, eslot, E, N);

    int nb = cdiv(N, 256);
    k_scan1<<<nb, 256, 0, stream>>>(deg, off, bsum, dinv, N);
    k_scan2<<<1, 1024, 0, stream>>>(bsum, nb);
    k_scan3<<<nb, 256, 0, stream>>>(off, bsum, N, E);
    k_scanG<<<1, 1024, 0, stream>>>(cnt, goff, G, N);

    int chunk = cdiv(N, 8);
    k_fill<<<cdiv(E, FILL_EPB) * 8, 256, 0, stream>>>(src, dst, off, eslot, csr, E, chunk);

    k_gemm<<<cdiv(N, 16), 256, 0, stream>>>(x, W1, bufA, N, 0);
    k_gather<<<cdiv(N, 4), 256, 0, stream>>>(bufA, csr, off, dinv, b1, bufB, N);

    k_gemm<<<cdiv(N, 16), 256, 0, stream>>>(bufB, W2, bufA, N, 1);
    k_gather<<<cdiv(N, 4), 256, 0, stream>>>(bufA, csr, off, dinv, b2, bufB, N);

    k_pool<<<cdiv(G, 4), 256, 0, stream>>>(bufB, goff, out, G);
}

// Round 6
// 410.190 us; speedup vs baseline: 7.5315x; 1.0108x over previous
//
#include <hip/hip_runtime.h>

#define DIM 64
#define FILL_EPB 2048

// ---------------- degree by dst, dst-range partitioned (XCD-local atomics) ----------------
// blockIdx&7 = range id; round-robin block->XCD keeps each deg line on one XCD's L2.

__global__ __launch_bounds__(256) void k_deg(const int* __restrict__ dst,
                                             int* __restrict__ deg, int E, int chunk) {
    int r = blockIdx.x & 7;
    int s = blockIdx.x >> 3;
    int rlo = r * chunk, rhi = rlo + chunk;
    int e0 = s * FILL_EPB;
    int e1 = e0 + FILL_EPB; if (e1 > E) e1 = E;
    for (int e = e0 + (int)threadIdx.x; e < e1; e += 256) {
        int t = dst[e];
        if (t >= rlo && t < rhi) atomicAdd(&deg[t], 1);
    }
}

// ---------------- graph boundaries from sorted batch (no atomics) ----------------
// goff[g] = first node index with batch >= g; goff[G] = N.

__global__ __launch_bounds__(256) void k_gbound(const int* __restrict__ batch,
                                                int* __restrict__ goff, int N, int G) {
    int i = blockIdx.x * 256 + threadIdx.x;
    if (i >= N) return;
    int b = batch[i];
    int prev = (i == 0) ? -1 : batch[i - 1];
    for (int g = prev + 1; g <= b; ++g) goff[g] = i;
    if (i == N - 1) {
        for (int g = b + 1; g <= G; ++g) goff[g] = N;
    }
}

// ---------------- exclusive scan over deg[N] -> off[N+1]; also dinv ----------------

__global__ __launch_bounds__(256) void k_scan1(const int* __restrict__ deg,
                                               int* __restrict__ off,
                                               int* __restrict__ bsum,
                                               float* __restrict__ dinv, int N) {
    __shared__ int s[256];
    int tid = threadIdx.x;
    int i = blockIdx.x * 256 + tid;
    int v = (i < N) ? deg[i] : 0;
    if (i < N) dinv[i] = rsqrtf((float)(v + 1));  // +1 self-loop
    s[tid] = v;
    __syncthreads();
#pragma unroll
    for (int d = 1; d < 256; d <<= 1) {
        int t = (tid >= d) ? s[tid - d] : 0;
        __syncthreads();
        s[tid] += t;
        __syncthreads();
    }
    if (i < N) off[i] = s[tid] - v;
    if (tid == 255) bsum[blockIdx.x] = s[255];
}

__global__ __launch_bounds__(1024) void k_scan2(int* __restrict__ bsum, int nb) {
    __shared__ int s[1024];
    int tid = threadIdx.x;
    int v = (tid < nb) ? bsum[tid] : 0;
    s[tid] = v;
    __syncthreads();
#pragma unroll
    for (int d = 1; d < 1024; d <<= 1) {
        int t = (tid >= d) ? s[tid - d] : 0;
        __syncthreads();
        s[tid] += t;
        __syncthreads();
    }
    if (tid < nb) bsum[tid] = s[tid] - v;
}

__global__ __launch_bounds__(256) void k_scan3(int* __restrict__ off,
                                               const int* __restrict__ bsum,
                                               int N, int total) {
    int i = blockIdx.x * 256 + threadIdx.x;
    if (i < N) off[i] += bsum[blockIdx.x];
    if (i == N - 1) off[N] = total;
}

// ---------------- CSR fill, dst-range partitioned (cur atomics + csr stores XCD-local) ----------------

__global__ __launch_bounds__(256) void k_fill(const int* __restrict__ src,
                                              const int* __restrict__ dst,
                                              const int* __restrict__ off,
                                              int* __restrict__ cur,
                                              int* __restrict__ csr, int E, int chunk) {
    int r = blockIdx.x & 7;
    int s = blockIdx.x >> 3;
    int rlo = r * chunk, rhi = rlo + chunk;
    int e0 = s * FILL_EPB;
    int e1 = e0 + FILL_EPB; if (e1 > E) e1 = E;
    for (int e = e0 + (int)threadIdx.x; e < e1; e += 256) {
        int t = dst[e];
        if (t >= rlo && t < rhi) {
            int slot = off[t] + atomicAdd(&cur[t], 1);
            csr[slot] = src[e];
        }
    }
}

// ---------------- skinny GEMM: Y[N,64] = (relu? relu(X) : X) @ W ----------------

__global__ __launch_bounds__(256) void k_gemm(const float* __restrict__ X,
                                              const float* __restrict__ W,
                                              float* __restrict__ Y, int N, int relu_in) {
    __shared__ float Ws[64 * 64];
    __shared__ float Xs[16 * 64];
    int tid = threadIdx.x;
#pragma unroll
    for (int i = 0; i < 16; ++i) Ws[tid + 256 * i] = W[tid + 256 * i];

    int row0 = blockIdx.x * 16;
    int r = tid >> 4, c4 = (tid & 15) << 2;
    {
        float4 v = make_float4(0.f, 0.f, 0.f, 0.f);
        if (row0 + r < N) v = *(const float4*)(X + (size_t)(row0 + r) * DIM + c4);
        if (relu_in) {
            v.x = fmaxf(v.x, 0.f); v.y = fmaxf(v.y, 0.f);
            v.z = fmaxf(v.z, 0.f); v.w = fmaxf(v.w, 0.f);
        }
        *(float4*)(Xs + r * DIM + c4) = v;
    }
    __syncthreads();

    float4 acc = make_float4(0.f, 0.f, 0.f, 0.f);
#pragma unroll
    for (int k = 0; k < 64; ++k) {
        float xk = Xs[r * DIM + k];
        float4 w = *(const float4*)(Ws + k * DIM + c4);
        acc.x += xk * w.x; acc.y += xk * w.y;
        acc.z += xk * w.z; acc.w += xk * w.w;
    }
    if (row0 + r < N) *(float4*)(Y + (size_t)(row0 + r) * DIM + c4) = acc;
}

// ---------------- gather: wave per node, staged indices + 8-wide MLP ----------------

__global__ __launch_bounds__(256) void k_gather(const float* __restrict__ h,
                                                const int* __restrict__ csr_src,
                                                const int* __restrict__ off,
                                                const float* __restrict__ dinv,
                                                const float* __restrict__ b,
                                                float* __restrict__ agg, int N) {
    int v = (blockIdx.x * 256 + threadIdx.x) >> 6;
    int lane = threadIdx.x & 63;
    if (v >= N) return;
    float dv = dinv[v];
    float acc = h[((size_t)v << 6) + lane] * dv * dv + b[lane];
    int k0 = off[v], k1 = off[v + 1];

    for (int kb = k0; kb < k1; kb += 64) {
        int m = k1 - kb; if (m > 64) m = 64;
        int idx = 0; float wgt = 0.f;
        if (lane < m) {
            idx = csr_src[kb + lane];
            wgt = dinv[idx] * dv;
        }
        int mm = (m + 7) & ~7;
        for (int j = 0; j < mm; j += 8) {
            int s0 = __shfl(idx, j + 0), s1 = __shfl(idx, j + 1);
            int s2 = __shfl(idx, j + 2), s3 = __shfl(idx, j + 3);
            int s4 = __shfl(idx, j + 4), s5 = __shfl(idx, j + 5);
            int s6 = __shfl(idx, j + 6), s7 = __shfl(idx, j + 7);
            float w0 = __shfl(wgt, j + 0), w1 = __shfl(wgt, j + 1);
            float w2 = __shfl(wgt, j + 2), w3 = __shfl(wgt, j + 3);
            float w4 = __shfl(wgt, j + 4), w5 = __shfl(wgt, j + 5);
            float w6 = __shfl(wgt, j + 6), w7 = __shfl(wgt, j + 7);
            float v0 = h[((size_t)s0 << 6) + lane];
            float v1 = h[((size_t)s1 << 6) + lane];
            float v2 = h[((size_t)s2 << 6) + lane];
            float v3 = h[((size_t)s3 << 6) + lane];
            float v4 = h[((size_t)s4 << 6) + lane];
            float v5 = h[((size_t)s5 << 6) + lane];
            float v6 = h[((size_t)s6 << 6) + lane];
            float v7 = h[((size_t)s7 << 6) + lane];
            acc += v0 * w0; acc += v1 * w1; acc += v2 * w2; acc += v3 * w3;
            acc += v4 * w4; acc += v5 * w5; acc += v6 * w6; acc += v7 * w7;
        }
    }
    agg[((size_t)v << 6) + lane] = acc;
}

// ---------------- pool ----------------

__global__ __launch_bounds__(256) void k_pool(const float* __restrict__ agg,
                                              const int* __restrict__ goff,
                                              float* __restrict__ out, int G) {
    int g = blockIdx.x * 4 + (threadIdx.x >> 6);
    if (g >= G) return;
    int lane = threadIdx.x & 63;
    int q = lane >> 4, d4 = (lane & 15) << 2;
    int n0 = goff[g], n1 = goff[g + 1];
    float4 acc = make_float4(0.f, 0.f, 0.f, 0.f);
    for (int i = n0 + q; i < n1; i += 4) {
        float4 hv = *(const float4*)(agg + ((size_t)i << 6) + d4);
        acc.x += fmaxf(hv.x, 0.f); acc.y += fmaxf(hv.y, 0.f);
        acc.z += fmaxf(hv.z, 0.f); acc.w += fmaxf(hv.w, 0.f);
    }
    acc.x += __shfl_down(acc.x, 32); acc.y += __shfl_down(acc.y, 32);
    acc.z += __shfl_down(acc.z, 32); acc.w += __shfl_down(acc.w, 32);
    acc.x += __shfl_down(acc.x, 16); acc.y += __shfl_down(acc.y, 16);
    acc.z += __shfl_down(acc.z, 16); acc.w += __shfl_down(acc.w, 16);
    if (q == 0) {
        float inv = 1.0f / fmaxf((float)(n1 - n0), 1.0f);
        *(float4*)(out + ((size_t)g << 6) + d4) =
            make_float4(acc.x * inv, acc.y * inv, acc.z * inv, acc.w * inv);
    }
}

// ---------------- launch ----------------

static inline int cdiv(int a, int b) { return (a + b - 1) / b; }

extern "C" void kernel_launch(void* const* d_in, const int* in_sizes, int n_in,
                              void* d_out, int out_size, void* d_ws, size_t ws_size,
                              hipStream_t stream) {
    const float* x   = (const float*)d_in[0];
    const float* W1  = (const float*)d_in[1];
    const float* b1  = (const float*)d_in[2];
    const float* W2  = (const float*)d_in[3];
    const float* b2  = (const float*)d_in[4];
    const int*   ei  = (const int*)d_in[5];
    const int*   bat = (const int*)d_in[6];

    const int N = in_sizes[0] / DIM;
    const int E = in_sizes[5] / 2;
    const int G = out_size / DIM;
    const int* src = ei;
    const int* dst = ei + E;
    float* out = (float*)d_out;

    // workspace: bufA | bufB | dinv | [deg cur] (one memset) | off | goff | bsum | csr
    float* bufA  = (float*)d_ws;                   // N*64 f
    float* bufB  = bufA + (size_t)N * DIM;         // N*64 f
    float* dinv  = bufB + (size_t)N * DIM;         // N f
    int*   deg   = (int*)(dinv + N);               // N i  \ one memset
    int*   cur   = deg + N;                        // N i  /
    int*   off   = cur + N;                        // N+1 i
    int*   goff  = off + (N + 1);                  // G+1 i
    int*   bsum  = goff + (G + 1);                 // 1024 i
    int*   csr   = bsum + 1024;                    // E i

    (void)hipMemsetAsync(deg, 0, (size_t)(2 * N) * sizeof(int), stream);

    int chunk = cdiv(N, 8);
    int egrid = cdiv(E, FILL_EPB) * 8;
    k_deg<<<egrid, 256, 0, stream>>>(dst, deg, E, chunk);
    k_gbound<<<cdiv(N, 256), 256, 0, stream>>>(bat, goff, N, G);

    int nb = cdiv(N, 256);
    k_scan1<<<nb, 256, 0, stream>>>(deg, off, bsum, dinv, N);
    k_scan2<<<1, 1024, 0, stream>>>(bsum, nb);
    k_scan3<<<nb, 256, 0, stream>>>(off, bsum, N, E);

    k_fill<<<egrid, 256, 0, stream>>>(src, dst, off, cur, csr, E, chunk);

    k_gemm<<<cdiv(N, 16), 256, 0, stream>>>(x, W1, bufA, N, 0);
    k_gather<<<cdiv(N, 4), 256, 0, stream>>>(bufA, csr, off, dinv, b1, bufB, N);

    k_gemm<<<cdiv(N, 16), 256, 0, stream>>>(bufB, W2, bufA, N, 1);
    k_gather<<<cdiv(N, 4), 256, 0, stream>>>(bufA, csr, off, dinv, b2, bufB, N);

    k_pool<<<cdiv(G, 4), 256, 0, stream>>>(bufB, goff, out, G);
}

// Round 7
// 337.231 us; speedup vs baseline: 9.1609x; 1.2163x over previous
//
#include <hip/hip_runtime.h>

#define DIM 64
#define BIN_SHIFT 6
#define MAXBINS 4096   // supports N up to 262144
#define PSLICE 128     // edge-slice blocks for hist/bucket

// ---------------- pass 1: LDS histogram over bins (bin = dst>>6) ----------------

__global__ __launch_bounds__(256) void k_hist(const int* __restrict__ dst,
                                              int* __restrict__ bin_hist,
                                              int E, int NB) {
    __shared__ int h[MAXBINS];
    for (int i = threadIdx.x; i < NB; i += 256) h[i] = 0;
    __syncthreads();
    int per = (E + PSLICE - 1) / PSLICE;
    int e0 = blockIdx.x * per;
    int e1 = e0 + per; if (e1 > E) e1 = E;
    for (int e = e0 + (int)threadIdx.x; e < e1; e += 256)
        atomicAdd(&h[dst[e] >> BIN_SHIFT], 1);
    __syncthreads();
    for (int i = threadIdx.x; i < NB; i += 256) {
        int c = h[i];
        if (c) atomicAdd(&bin_hist[i], c);
    }
}

// ---------------- pass 2: exclusive scan of bin_hist -> binoff[NB+1]; off[N]=E ----------------

__global__ __launch_bounds__(1024) void k_scanbins(const int* __restrict__ bin_hist,
                                                   int* __restrict__ binoff,
                                                   int* __restrict__ offN,
                                                   int NB, int E) {
    __shared__ int s[1024];
    int tid = threadIdx.x;
    int base_i = tid * 4;
    int v[4]; int sum = 0;
#pragma unroll
    for (int j = 0; j < 4; ++j) {
        int idx = base_i + j;
        int x = (idx < NB) ? bin_hist[idx] : 0;
        v[j] = sum; sum += x;
    }
    s[tid] = sum;
    __syncthreads();
#pragma unroll
    for (int d = 1; d < 1024; d <<= 1) {
        int t = (tid >= d) ? s[tid - d] : 0;
        __syncthreads();
        s[tid] += t;
        __syncthreads();
    }
    int excl = s[tid] - sum;
#pragma unroll
    for (int j = 0; j < 4; ++j) {
        int idx = base_i + j;
        if (idx < NB) binoff[idx] = excl + v[j];
    }
    if (tid == 0) { binoff[NB] = E; offN[0] = E; }
}

// ---------------- pass 3: bucket edges by bin (packed (dst&63)<<24 | src) ----------------

__global__ __launch_bounds__(256) void k_bucket(const int* __restrict__ src,
                                                const int* __restrict__ dst,
                                                const int* __restrict__ binoff,
                                                int* __restrict__ bin_cur,
                                                int* __restrict__ bkt,
                                                int E, int NB) {
    __shared__ int h[MAXBINS];     // local count, then global base for this block
    __shared__ int lcur[MAXBINS];  // local running cursor
    for (int i = threadIdx.x; i < NB; i += 256) { h[i] = 0; lcur[i] = 0; }
    __syncthreads();
    int per = (E + PSLICE - 1) / PSLICE;
    int e0 = blockIdx.x * per;
    int e1 = e0 + per; if (e1 > E) e1 = E;
    for (int e = e0 + (int)threadIdx.x; e < e1; e += 256)
        atomicAdd(&h[dst[e] >> BIN_SHIFT], 1);
    __syncthreads();
    for (int i = threadIdx.x; i < NB; i += 256) {
        int c = h[i];
        if (c) h[i] = atomicAdd(&bin_cur[i], c);   // claim run [base, base+c)
    }
    __syncthreads();
    for (int e = e0 + (int)threadIdx.x; e < e1; e += 256) {
        int d = dst[e];
        int b = d >> BIN_SHIFT;
        int li = atomicAdd(&lcur[b], 1);
        int pos = binoff[b] + h[b] + li;
        bkt[pos] = src[e] | ((d & 63) << 24);
    }
}

// ---------------- pass 4: per-bin exact counting sort -> csr, off, dinv ----------------

__global__ __launch_bounds__(256) void k_binsort(const int* __restrict__ bkt,
                                                 const int* __restrict__ binoff,
                                                 int* __restrict__ csr,
                                                 int* __restrict__ off,
                                                 float* __restrict__ dinv, int N) {
    __shared__ int cnt[64], bas[64], cur[64];
    int b = blockIdx.x;
    int s0 = binoff[b], s1 = binoff[b + 1];
    if (threadIdx.x < 64) { cnt[threadIdx.x] = 0; cur[threadIdx.x] = 0; }
    __syncthreads();
    for (int i = s0 + (int)threadIdx.x; i < s1; i += 256)
        atomicAdd(&cnt[(bkt[i] >> 24) & 63], 1);
    __syncthreads();
    if (threadIdx.x == 0) {
        int run = 0;
        for (int l = 0; l < 64; ++l) { bas[l] = run; run += cnt[l]; }
    }
    __syncthreads();
    if (threadIdx.x < 64) {
        int v = (b << BIN_SHIFT) + threadIdx.x;
        if (v < N) {
            off[v] = s0 + bas[threadIdx.x];
            dinv[v] = rsqrtf((float)(cnt[threadIdx.x] + 1));  // +1 self-loop
        }
    }
    for (int i = s0 + (int)threadIdx.x; i < s1; i += 256) {
        int p = bkt[i];
        int lo = (p >> 24) & 63;
        int li = atomicAdd(&cur[lo], 1);
        csr[s0 + bas[lo] + li] = p & 0xFFFFFF;
    }
}

// ---------------- graph boundaries from sorted batch (no atomics) ----------------

__global__ __launch_bounds__(256) void k_gbound(const int* __restrict__ batch,
                                                int* __restrict__ goff, int N, int G) {
    int i = blockIdx.x * 256 + threadIdx.x;
    if (i >= N) return;
    int b = batch[i];
    int prev = (i == 0) ? -1 : batch[i - 1];
    for (int g = prev + 1; g <= b; ++g) goff[g] = i;
    if (i == N - 1) {
        for (int g = b + 1; g <= G; ++g) goff[g] = N;
    }
}

// ---------------- skinny GEMM: Y[N,64] = (relu? relu(X) : X) @ W ----------------

__global__ __launch_bounds__(256) void k_gemm(const float* __restrict__ X,
                                              const float* __restrict__ W,
                                              float* __restrict__ Y, int N, int relu_in) {
    __shared__ float Ws[64 * 64];
    __shared__ float Xs[16 * 64];
    int tid = threadIdx.x;
#pragma unroll
    for (int i = 0; i < 16; ++i) Ws[tid + 256 * i] = W[tid + 256 * i];

    int row0 = blockIdx.x * 16;
    int r = tid >> 4, c4 = (tid & 15) << 2;
    {
        float4 v = make_float4(0.f, 0.f, 0.f, 0.f);
        if (row0 + r < N) v = *(const float4*)(X + (size_t)(row0 + r) * DIM + c4);
        if (relu_in) {
            v.x = fmaxf(v.x, 0.f); v.y = fmaxf(v.y, 0.f);
            v.z = fmaxf(v.z, 0.f); v.w = fmaxf(v.w, 0.f);
        }
        *(float4*)(Xs + r * DIM + c4) = v;
    }
    __syncthreads();

    float4 acc = make_float4(0.f, 0.f, 0.f, 0.f);
#pragma unroll
    for (int k = 0; k < 64; ++k) {
        float xk = Xs[r * DIM + k];
        float4 w = *(const float4*)(Ws + k * DIM + c4);
        acc.x += xk * w.x; acc.y += xk * w.y;
        acc.z += xk * w.z; acc.w += xk * w.w;
    }
    if (row0 + r < N) *(float4*)(Y + (size_t)(row0 + r) * DIM + c4) = acc;
}

// ---------------- gather: wave per node, staged indices + 8-wide MLP ----------------

__global__ __launch_bounds__(256) void k_gather(const float* __restrict__ h,
                                                const int* __restrict__ csr_src,
                                                const int* __restrict__ off,
                                                const float* __restrict__ dinv,
                                                const float* __restrict__ b,
                                                float* __restrict__ agg, int N) {
    int v = (blockIdx.x * 256 + threadIdx.x) >> 6;
    int lane = threadIdx.x & 63;
    if (v >= N) return;
    float dv = dinv[v];
    float acc = h[((size_t)v << 6) + lane] * dv * dv + b[lane];
    int k0 = off[v], k1 = off[v + 1];

    for (int kb = k0; kb < k1; kb += 64) {
        int m = k1 - kb; if (m > 64) m = 64;
        int idx = 0; float wgt = 0.f;
        if (lane < m) {
            idx = csr_src[kb + lane];
            wgt = dinv[idx] * dv;
        }
        int mm = (m + 7) & ~7;
        for (int j = 0; j < mm; j += 8) {
            int s0 = __shfl(idx, j + 0), s1 = __shfl(idx, j + 1);
            int s2 = __shfl(idx, j + 2), s3 = __shfl(idx, j + 3);
            int s4 = __shfl(idx, j + 4), s5 = __shfl(idx, j + 5);
            int s6 = __shfl(idx, j + 6), s7 = __shfl(idx, j + 7);
            float w0 = __shfl(wgt, j + 0), w1 = __shfl(wgt, j + 1);
            float w2 = __shfl(wgt, j + 2), w3 = __shfl(wgt, j + 3);
            float w4 = __shfl(wgt, j + 4), w5 = __shfl(wgt, j + 5);
            float w6 = __shfl(wgt, j + 6), w7 = __shfl(wgt, j + 7);
            float v0 = h[((size_t)s0 << 6) + lane];
            float v1 = h[((size_t)s1 << 6) + lane];
            float v2 = h[((size_t)s2 << 6) + lane];
            float v3 = h[((size_t)s3 << 6) + lane];
            float v4 = h[((size_t)s4 << 6) + lane];
            float v5 = h[((size_t)s5 << 6) + lane];
            float v6 = h[((size_t)s6 << 6) + lane];
            float v7 = h[((size_t)s7 << 6) + lane];
            acc += v0 * w0; acc += v1 * w1; acc += v2 * w2; acc += v3 * w3;
            acc += v4 * w4; acc += v5 * w5; acc += v6 * w6; acc += v7 * w7;
        }
    }
    agg[((size_t)v << 6) + lane] = acc;
}

// ---------------- pool ----------------

__global__ __launch_bounds__(256) void k_pool(const float* __restrict__ agg,
                                              const int* __restrict__ goff,
                                              float* __restrict__ out, int G) {
    int g = blockIdx.x * 4 + (threadIdx.x >> 6);
    if (g >= G) return;
    int lane = threadIdx.x & 63;
    int q = lane >> 4, d4 = (lane & 15) << 2;
    int n0 = goff[g], n1 = goff[g + 1];
    float4 acc = make_float4(0.f, 0.f, 0.f, 0.f);
    for (int i = n0 + q; i < n1; i += 4) {
        float4 hv = *(const float4*)(agg + ((size_t)i << 6) + d4);
        acc.x += fmaxf(hv.x, 0.f); acc.y += fmaxf(hv.y, 0.f);
        acc.z += fmaxf(hv.z, 0.f); acc.w += fmaxf(hv.w, 0.f);
    }
    acc.x += __shfl_down(acc.x, 32); acc.y += __shfl_down(acc.y, 32);
    acc.z += __shfl_down(acc.z, 32); acc.w += __shfl_down(acc.w, 32);
    acc.x += __shfl_down(acc.x, 16); acc.y += __shfl_down(acc.y, 16);
    acc.z += __shfl_down(acc.z, 16); acc.w += __shfl_down(acc.w, 16);
    if (q == 0) {
        float inv = 1.0f / fmaxf((float)(n1 - n0), 1.0f);
        *(float4*)(out + ((size_t)g << 6) + d4) =
            make_float4(acc.x * inv, acc.y * inv, acc.z * inv, acc.w * inv);
    }
}

// ---------------- launch ----------------

static inline int cdiv(int a, int b) { return (a + b - 1) / b; }

extern "C" void kernel_launch(void* const* d_in, const int* in_sizes, int n_in,
                              void* d_out, int out_size, void* d_ws, size_t ws_size,
                              hipStream_t stream) {
    const float* x   = (const float*)d_in[0];
    const float* W1  = (const float*)d_in[1];
    const float* b1  = (const float*)d_in[2];
    const float* W2  = (const float*)d_in[3];
    const float* b2  = (const float*)d_in[4];
    const int*   ei  = (const int*)d_in[5];
    const int*   bat = (const int*)d_in[6];

    const int N = in_sizes[0] / DIM;
    const int E = in_sizes[5] / 2;
    const int G = out_size / DIM;
    const int NB = cdiv(N, 1 << BIN_SHIFT);   // bins of 64 nodes; NB <= MAXBINS
    const int* src = ei;
    const int* dst = ei + E;
    float* out = (float*)d_out;

    // workspace: bufA | bufB | dinv | off | goff | [binhist bincur] (one memset) | csr
    // bkt (E ints) aliases bufA: bucket/binsort finish before gemm writes bufA.
    float* bufA    = (float*)d_ws;                 // N*64 f
    float* bufB    = bufA + (size_t)N * DIM;       // N*64 f
    float* dinv    = bufB + (size_t)N * DIM;       // N f
    int*   off     = (int*)(dinv + N);             // N+1 i
    int*   goff    = off + (N + 1);                // G+1 i
    int*   binhist = goff + (G + 1);               // MAXBINS i \ one memset
    int*   bincur  = binhist + MAXBINS;            // MAXBINS i /
    int*   binoff  = bincur + MAXBINS;             // MAXBINS+1 i
    int*   csr     = binoff + (MAXBINS + 1);       // E i
    int*   bkt     = (int*)bufA;                   // E i (aliased)

    (void)hipMemsetAsync(binhist, 0, 2 * MAXBINS * sizeof(int), stream);

    k_hist<<<PSLICE, 256, 0, stream>>>(dst, binhist, E, NB);
    k_scanbins<<<1, 1024, 0, stream>>>(binhist, binoff, off + N, NB, E);
    k_bucket<<<PSLICE, 256, 0, stream>>>(src, dst, binoff, bincur, bkt, E, NB);
    k_binsort<<<NB, 256, 0, stream>>>(bkt, binoff, csr, off, dinv, N);
    k_gbound<<<cdiv(N, 256), 256, 0, stream>>>(bat, goff, N, G);

    k_gemm<<<cdiv(N, 16), 256, 0, stream>>>(x, W1, bufA, N, 0);
    k_gather<<<cdiv(N, 4), 256, 0, stream>>>(bufA, csr, off, dinv, b1, bufB, N);

    k_gemm<<<cdiv(N, 16), 256, 0, stream>>>(bufB, W2, bufA, N, 1);
    k_gather<<<cdiv(N, 4), 256, 0, stream>>>(bufA, csr, off, dinv, b2, bufB, N);

    k_pool<<<cdiv(G, 4), 256, 0, stream>>>(bufB, goff, out, G);
}

// Round 8
// 316.860 us; speedup vs baseline: 9.7498x; 1.0643x over previous
//
#include <hip/hip_runtime.h>

#define DIM 64
#define BIN_SHIFT 6
#define MAXBINS 4096   // supports N up to 262144
#define PB 512         // edge-slice blocks for hist/bucket (power of 2)
#define PB_LOG 9

// ---------------- pass 1: per-block LDS histogram -> C[blk][bin] (coalesced) ----------------

__global__ __launch_bounds__(256) void k_hist(const int* __restrict__ dst,
                                              int* __restrict__ C, int E, int NB) {
    __shared__ int h[MAXBINS];
    for (int i = threadIdx.x; i < NB; i += 256) h[i] = 0;
    __syncthreads();
    int per = (E + PB - 1) / PB;
    int e0 = blockIdx.x * per;
    int e1 = e0 + per; if (e1 > E) e1 = E;
    for (int e = e0 + (int)threadIdx.x; e < e1; e += 256)
        atomicAdd(&h[dst[e] >> BIN_SHIFT], 1);
    __syncthreads();
    for (int i = threadIdx.x; i < NB; i += 256)
        C[blockIdx.x * NB + i] = h[i];
}

// ---------------- pass 2: exclusive scan of C in bin-major logical order ----------------
// logical j: bin = j>>PB_LOG, blk = j&(PB-1); physical C[blk*NB+bin].
// S[j] = global start of run (bin,blk). binoff[b] = S[b*PB].

__global__ __launch_bounds__(1024) void k_scanA(const int* __restrict__ C,
                                                int* __restrict__ S,
                                                int* __restrict__ bsums, int NB, int M) {
    __shared__ int sh[1024];
    int tid = threadIdx.x;
    int j0 = blockIdx.x * 4096 + tid * 4;
    int v[4]; int sum = 0;
#pragma unroll
    for (int t = 0; t < 4; ++t) {
        int j = j0 + t; int x = 0;
        if (j < M) { int bin = j >> PB_LOG, blk = j & (PB - 1); x = C[blk * NB + bin]; }
        v[t] = sum; sum += x;
    }
    sh[tid] = sum;
    __syncthreads();
#pragma unroll
    for (int d = 1; d < 1024; d <<= 1) {
        int t = (tid >= d) ? sh[tid - d] : 0;
        __syncthreads();
        sh[tid] += t;
        __syncthreads();
    }
    int excl = sh[tid] - sum;
#pragma unroll
    for (int t = 0; t < 4; ++t) {
        int j = j0 + t;
        if (j < M) S[j] = excl + v[t];
    }
    if (tid == 1023) bsums[blockIdx.x] = sh[1023];
}

__global__ __launch_bounds__(1024) void k_scanB(int* __restrict__ bsums, int nb) {
    __shared__ int s[1024];
    int tid = threadIdx.x;
    int v = (tid < nb) ? bsums[tid] : 0;
    s[tid] = v;
    __syncthreads();
#pragma unroll
    for (int d = 1; d < 1024; d <<= 1) {
        int t = (tid >= d) ? s[tid - d] : 0;
        __syncthreads();
        s[tid] += t;
        __syncthreads();
    }
    if (tid < nb) bsums[tid] = s[tid] - v;
}

__global__ __launch_bounds__(1024) void k_scanC(int* __restrict__ S,
                                                const int* __restrict__ bsums,
                                                int* __restrict__ binoff,
                                                int* __restrict__ offN,
                                                int NB, int M, int E) {
    int tid = threadIdx.x;
    int j0 = blockIdx.x * 4096 + tid * 4;
    int add = bsums[blockIdx.x];
#pragma unroll
    for (int t = 0; t < 4; ++t) {
        int j = j0 + t;
        if (j < M) {
            int val = S[j] + add;
            S[j] = val;
            if ((j & (PB - 1)) == 0) binoff[j >> PB_LOG] = val;
        }
    }
    if (blockIdx.x == 0 && tid == 0) { binoff[NB] = E; offN[0] = E; }
}

// ---------------- pass 3: one-pass bucket scatter, LDS cursors, NO global atomics ----------------

__global__ __launch_bounds__(256) void k_bucket(const int* __restrict__ src,
                                                const int* __restrict__ dst,
                                                const int* __restrict__ S,
                                                int* __restrict__ bkt, int E, int NB) {
    __shared__ int lcur[MAXBINS];
    int blk = blockIdx.x;
    for (int i = threadIdx.x; i < NB; i += 256)
        lcur[i] = S[i * PB + blk];               // exact global base of run (bin,blk)
    __syncthreads();
    int per = (E + PB - 1) / PB;
    int e0 = blk * per;
    int e1 = e0 + per; if (e1 > E) e1 = E;
    for (int e = e0 + (int)threadIdx.x; e < e1; e += 256) {
        int d = dst[e];
        int pos = atomicAdd(&lcur[d >> BIN_SHIFT], 1);
        bkt[pos] = src[e] | ((d & 63) << 24);
    }
}

// ---------------- pass 4: per-bin exact counting sort -> csr, off, dinv ----------------

__global__ __launch_bounds__(256) void k_binsort(const int* __restrict__ bkt,
                                                 const int* __restrict__ binoff,
                                                 int* __restrict__ csr,
                                                 int* __restrict__ off,
                                                 float* __restrict__ dinv, int N) {
    __shared__ int cnt[64], bas[64], cur[64];
    int b = blockIdx.x;
    int s0 = binoff[b], s1 = binoff[b + 1];
    if (threadIdx.x < 64) { cnt[threadIdx.x] = 0; cur[threadIdx.x] = 0; }
    __syncthreads();
    for (int i = s0 + (int)threadIdx.x; i < s1; i += 256)
        atomicAdd(&cnt[(bkt[i] >> 24) & 63], 1);
    __syncthreads();
    if (threadIdx.x == 0) {
        int run = 0;
        for (int l = 0; l < 64; ++l) { bas[l] = run; run += cnt[l]; }
    }
    __syncthreads();
    if (threadIdx.x < 64) {
        int v = (b << BIN_SHIFT) + threadIdx.x;
        if (v < N) {
            off[v] = s0 + bas[threadIdx.x];
            dinv[v] = rsqrtf((float)(cnt[threadIdx.x] + 1));  // +1 self-loop
        }
    }
    for (int i = s0 + (int)threadIdx.x; i < s1; i += 256) {
        int p = bkt[i];
        int lo = (p >> 24) & 63;
        int li = atomicAdd(&cur[lo], 1);
        csr[s0 + bas[lo] + li] = p & 0xFFFFFF;
    }
}

// ---------------- graph boundaries from sorted batch ----------------

__global__ __launch_bounds__(256) void k_gbound(const int* __restrict__ batch,
                                                int* __restrict__ goff, int N, int G) {
    int i = blockIdx.x * 256 + threadIdx.x;
    if (i >= N) return;
    int b = batch[i];
    int prev = (i == 0) ? -1 : batch[i - 1];
    for (int g = prev + 1; g <= b; ++g) goff[g] = i;
    if (i == N - 1) {
        for (int g = b + 1; g <= G; ++g) goff[g] = N;
    }
}

// ---------------- skinny GEMM: Y[N,64] = (relu? relu(X) : X) @ W ----------------

__global__ __launch_bounds__(256) void k_gemm(const float* __restrict__ X,
                                              const float* __restrict__ W,
                                              float* __restrict__ Y, int N, int relu_in) {
    __shared__ float Ws[64 * 64];
    __shared__ float Xs[16 * 64];
    int tid = threadIdx.x;
#pragma unroll
    for (int i = 0; i < 16; ++i) Ws[tid + 256 * i] = W[tid + 256 * i];

    int row0 = blockIdx.x * 16;
    int r = tid >> 4, c4 = (tid & 15) << 2;
    {
        float4 v = make_float4(0.f, 0.f, 0.f, 0.f);
        if (row0 + r < N) v = *(const float4*)(X + (size_t)(row0 + r) * DIM + c4);
        if (relu_in) {
            v.x = fmaxf(v.x, 0.f); v.y = fmaxf(v.y, 0.f);
            v.z = fmaxf(v.z, 0.f); v.w = fmaxf(v.w, 0.f);
        }
        *(float4*)(Xs + r * DIM + c4) = v;
    }
    __syncthreads();

    float4 acc = make_float4(0.f, 0.f, 0.f, 0.f);
#pragma unroll
    for (int k = 0; k < 64; ++k) {
        float xk = Xs[r * DIM + k];
        float4 w = *(const float4*)(Ws + k * DIM + c4);
        acc.x += xk * w.x; acc.y += xk * w.y;
        acc.z += xk * w.z; acc.w += xk * w.w;
    }
    if (row0 + r < N) *(float4*)(Y + (size_t)(row0 + r) * DIM + c4) = acc;
}

// ---------------- gather v3: wave per node, float4 lanes, 4 edges per issue ----------------
// quarter q = lane>>4 handles edge j+q; 16 lanes * float4 cover the 64-dim row.

__global__ __launch_bounds__(256) void k_gather(const float* __restrict__ h,
                                                const int* __restrict__ csr_src,
                                                const int* __restrict__ off,
                                                const float* __restrict__ dinv,
                                                const float* __restrict__ b,
                                                float* __restrict__ agg, int N) {
    int v = (blockIdx.x * 256 + threadIdx.x) >> 6;
    int lane = threadIdx.x & 63;
    if (v >= N) return;
    int q = lane >> 4, c = lane & 15;
    const float4* h4 = (const float4*)h;
    float dv = dinv[v];

    float4 acc = make_float4(0.f, 0.f, 0.f, 0.f);
    if (q == 0) {                      // self-loop + bias on quarter 0 only
        float4 hv = h4[(size_t)v * 16 + c];
        float4 bv = ((const float4*)b)[c];
        float n = dv * dv;
        acc = make_float4(hv.x * n + bv.x, hv.y * n + bv.y,
                          hv.z * n + bv.z, hv.w * n + bv.w);
    }

    int k0 = off[v], k1 = off[v + 1];
    for (int kb = k0; kb < k1; kb += 64) {
        int m = k1 - kb; if (m > 64) m = 64;
        int idx = 0; float wgt = 0.f;
        if (lane < m) {
            idx = csr_src[kb + lane];
            wgt = dinv[idx] * dv;
        }
        int mm = (m + 7) & ~7;
        for (int j = 0; j < mm; j += 8) {   // 8 edges per iter: 2 float4 gathers/lane
            int   sA = __shfl(idx, j + q);
            float wA = __shfl(wgt, j + q);
            int   sB = __shfl(idx, j + 4 + q);
            float wB = __shfl(wgt, j + 4 + q);
            float4 a0 = h4[(size_t)sA * 16 + c];
            float4 a1 = h4[(size_t)sB * 16 + c];
            acc.x += a0.x * wA; acc.y += a0.y * wA;
            acc.z += a0.z * wA; acc.w += a0.w * wA;
            acc.x += a1.x * wB; acc.y += a1.y * wB;
            acc.z += a1.z * wB; acc.w += a1.w * wB;
        }
    }
    // reduce quarters: lanes (c, c+16, c+32, c+48) -> lane c
    acc.x += __shfl_down(acc.x, 32); acc.y += __shfl_down(acc.y, 32);
    acc.z += __shfl_down(acc.z, 32); acc.w += __shfl_down(acc.w, 32);
    acc.x += __shfl_down(acc.x, 16); acc.y += __shfl_down(acc.y, 16);
    acc.z += __shfl_down(acc.z, 16); acc.w += __shfl_down(acc.w, 16);
    if (q == 0) *(float4*)(agg + ((size_t)v << 6) + (c << 2)) = acc;
}

// ---------------- pool ----------------

__global__ __launch_bounds__(256) void k_pool(const float* __restrict__ agg,
                                              const int* __restrict__ goff,
                                              float* __restrict__ out, int G) {
    int g = blockIdx.x * 4 + (threadIdx.x >> 6);
    if (g >= G) return;
    int lane = threadIdx.x & 63;
    int q = lane >> 4, d4 = (lane & 15) << 2;
    int n0 = goff[g], n1 = goff[g + 1];
    float4 acc = make_float4(0.f, 0.f, 0.f, 0.f);
    for (int i = n0 + q; i < n1; i += 4) {
        float4 hv = *(const float4*)(agg + ((size_t)i << 6) + d4);
        acc.x += fmaxf(hv.x, 0.f); acc.y += fmaxf(hv.y, 0.f);
        acc.z += fmaxf(hv.z, 0.f); acc.w += fmaxf(hv.w, 0.f);
    }
    acc.x += __shfl_down(acc.x, 32); acc.y += __shfl_down(acc.y, 32);
    acc.z += __shfl_down(acc.z, 32); acc.w += __shfl_down(acc.w, 32);
    acc.x += __shfl_down(acc.x, 16); acc.y += __shfl_down(acc.y, 16);
    acc.z += __shfl_down(acc.z, 16); acc.w += __shfl_down(acc.w, 16);
    if (q == 0) {
        float inv = 1.0f / fmaxf((float)(n1 - n0), 1.0f);
        *(float4*)(out + ((size_t)g << 6) + d4) =
            make_float4(acc.x * inv, acc.y * inv, acc.z * inv, acc.w * inv);
    }
}

// ---------------- launch ----------------

static inline int cdiv(int a, int b) { return (a + b - 1) / b; }

extern "C" void kernel_launch(void* const* d_in, const int* in_sizes, int n_in,
                              void* d_out, int out_size, void* d_ws, size_t ws_size,
                              hipStream_t stream) {
    const float* x   = (const float*)d_in[0];
    const float* W1  = (const float*)d_in[1];
    const float* b1  = (const float*)d_in[2];
    const float* W2  = (const float*)d_in[3];
    const float* b2  = (const float*)d_in[4];
    const int*   ei  = (const int*)d_in[5];
    const int*   bat = (const int*)d_in[6];

    const int N = in_sizes[0] / DIM;
    const int E = in_sizes[5] / 2;
    const int G = out_size / DIM;
    const int NB = cdiv(N, 1 << BIN_SHIFT);   // <= MAXBINS
    const int M  = NB * PB;                   // scan length
    const int* src = ei;
    const int* dst = ei + E;
    float* out = (float*)d_out;

    // workspace: bufA | bufB | dinv | off | goff | binoff | C | S | bsums | csr
    // bkt aliases bufA (bucket/binsort finish before gemm writes bufA).
    float* bufA   = (float*)d_ws;                 // N*64 f
    float* bufB   = bufA + (size_t)N * DIM;       // N*64 f
    float* dinv   = bufB + (size_t)N * DIM;       // N f
    int*   off    = (int*)(dinv + N);             // N+1 i
    int*   goff   = off + (N + 1);                // G+1 i
    int*   binoff = goff + (G + 1);               // NB+1 i
    int*   C      = binoff + (NB + 1);            // PB*NB i
    int*   S      = C + (size_t)PB * NB;          // PB*NB i
    int*   bsums  = S + (size_t)PB * NB;          // up to 1024 i
    int*   csr    = bsums + 1024;                 // E i
    int*   bkt    = (int*)bufA;                   // E i (aliased)

    k_hist<<<PB, 256, 0, stream>>>(dst, C, E, NB);
    int nb2 = cdiv(M, 4096);
    k_scanA<<<nb2, 1024, 0, stream>>>(C, S, bsums, NB, M);
    k_scanB<<<1, 1024, 0, stream>>>(bsums, nb2);
    k_scanC<<<nb2, 1024, 0, stream>>>(S, bsums, binoff, off + N, NB, M, E);
    k_bucket<<<PB, 256, 0, stream>>>(src, dst, S, bkt, E, NB);
    k_binsort<<<NB, 256, 0, stream>>>(bkt, binoff, csr, off, dinv, N);
    k_gbound<<<cdiv(N, 256), 256, 0, stream>>>(bat, goff, N, G);

    k_gemm<<<cdiv(N, 16), 256, 0, stream>>>(x, W1, bufA, N, 0);
    k_gather<<<cdiv(N, 4), 256, 0, stream>>>(bufA, csr, off, dinv, b1, bufB, N);

    k_gemm<<<cdiv(N, 16), 256, 0, stream>>>(bufB, W2, bufA, N, 1);
    k_gather<<<cdiv(N, 4), 256, 0, stream>>>(bufA, csr, off, dinv, b2, bufB, N);

    k_pool<<<cdiv(G, 4), 256, 0, stream>>>(bufB, goff, out, G);
}

// Round 9
// 285.341 us; speedup vs baseline: 10.8268x; 1.1105x over previous
//
#include <hip/hip_runtime.h>
#include <hip/hip_fp16.h>

#define DIM 64
#define BIN_SHIFT 6
#define MAXBINS 4096   // supports N up to 262144
#define PB 512         // edge-slice blocks for hist/bucket (power of 2)
#define PB_LOG 9

// ---------------- pass 1: per-block LDS histogram -> C[blk][bin] (coalesced) ----------------

__global__ __launch_bounds__(256) void k_hist(const int* __restrict__ dst,
                                              int* __restrict__ C, int E, int NB) {
    __shared__ int h[MAXBINS];
    for (int i = threadIdx.x; i < NB; i += 256) h[i] = 0;
    __syncthreads();
    int per = (E + PB - 1) / PB;
    int e0 = blockIdx.x * per;
    int e1 = e0 + per; if (e1 > E) e1 = E;
    for (int e = e0 + (int)threadIdx.x; e < e1; e += 256)
        atomicAdd(&h[dst[e] >> BIN_SHIFT], 1);
    __syncthreads();
    for (int i = threadIdx.x; i < NB; i += 256)
        C[blockIdx.x * NB + i] = h[i];
}

// ---------------- pass 2: exclusive scan of C in bin-major logical order ----------------

__global__ __launch_bounds__(1024) void k_scanA(const int* __restrict__ C,
                                                int* __restrict__ S,
                                                int* __restrict__ bsums, int NB, int M) {
    __shared__ int sh[1024];
    int tid = threadIdx.x;
    int j0 = blockIdx.x * 4096 + tid * 4;
    int v[4]; int sum = 0;
#pragma unroll
    for (int t = 0; t < 4; ++t) {
        int j = j0 + t; int x = 0;
        if (j < M) { int bin = j >> PB_LOG, blk = j & (PB - 1); x = C[blk * NB + bin]; }
        v[t] = sum; sum += x;
    }
    sh[tid] = sum;
    __syncthreads();
#pragma unroll
    for (int d = 1; d < 1024; d <<= 1) {
        int t = (tid >= d) ? sh[tid - d] : 0;
        __syncthreads();
        sh[tid] += t;
        __syncthreads();
    }
    int excl = sh[tid] - sum;
#pragma unroll
    for (int t = 0; t < 4; ++t) {
        int j = j0 + t;
        if (j < M) S[j] = excl + v[t];
    }
    if (tid == 1023) bsums[blockIdx.x] = sh[1023];
}

__global__ __launch_bounds__(1024) void k_scanB(int* __restrict__ bsums, int nb) {
    __shared__ int s[1024];
    int tid = threadIdx.x;
    int v = (tid < nb) ? bsums[tid] : 0;
    s[tid] = v;
    __syncthreads();
#pragma unroll
    for (int d = 1; d < 1024; d <<= 1) {
        int t = (tid >= d) ? s[tid - d] : 0;
        __syncthreads();
        s[tid] += t;
        __syncthreads();
    }
    if (tid < nb) bsums[tid] = s[tid] - v;
}

__global__ __launch_bounds__(1024) void k_scanC(int* __restrict__ S,
                                                const int* __restrict__ bsums,
                                                int* __restrict__ binoff,
                                                int* __restrict__ offN,
                                                int NB, int M, int E) {
    int tid = threadIdx.x;
    int j0 = blockIdx.x * 4096 + tid * 4;
    int add = bsums[blockIdx.x];
#pragma unroll
    for (int t = 0; t < 4; ++t) {
        int j = j0 + t;
        if (j < M) {
            int val = S[j] + add;
            S[j] = val;
            if ((j & (PB - 1)) == 0) binoff[j >> PB_LOG] = val;
        }
    }
    if (blockIdx.x == 0 && tid == 0) { binoff[NB] = E; offN[0] = E; }
}

// ---------------- pass 3: one-pass bucket scatter, LDS cursors, no global atomics ----------------

__global__ __launch_bounds__(256) void k_bucket(const int* __restrict__ src,
                                                const int* __restrict__ dst,
                                                const int* __restrict__ S,
                                                int* __restrict__ bkt, int E, int NB) {
    __shared__ int lcur[MAXBINS];
    int blk = blockIdx.x;
    for (int i = threadIdx.x; i < NB; i += 256)
        lcur[i] = S[i * PB + blk];
    __syncthreads();
    int per = (E + PB - 1) / PB;
    int e0 = blk * per;
    int e1 = e0 + per; if (e1 > E) e1 = E;
    for (int e = e0 + (int)threadIdx.x; e < e1; e += 256) {
        int d = dst[e];
        int pos = atomicAdd(&lcur[d >> BIN_SHIFT], 1);
        bkt[pos] = src[e] | ((d & 63) << 24);
    }
}

// ---------------- pass 4: per-bin exact counting sort -> csr, off, dinv ----------------

__global__ __launch_bounds__(256) void k_binsort(const int* __restrict__ bkt,
                                                 const int* __restrict__ binoff,
                                                 int* __restrict__ csr,
                                                 int* __restrict__ off,
                                                 float* __restrict__ dinv, int N) {
    __shared__ int cnt[64], bas[64], cur[64];
    int b = blockIdx.x;
    int s0 = binoff[b], s1 = binoff[b + 1];
    if (threadIdx.x < 64) { cnt[threadIdx.x] = 0; cur[threadIdx.x] = 0; }
    __syncthreads();
    for (int i = s0 + (int)threadIdx.x; i < s1; i += 256)
        atomicAdd(&cnt[(bkt[i] >> 24) & 63], 1);
    __syncthreads();
    if (threadIdx.x == 0) {
        int run = 0;
        for (int l = 0; l < 64; ++l) { bas[l] = run; run += cnt[l]; }
    }
    __syncthreads();
    if (threadIdx.x < 64) {
        int v = (b << BIN_SHIFT) + threadIdx.x;
        if (v < N) {
            off[v] = s0 + bas[threadIdx.x];
            dinv[v] = rsqrtf((float)(cnt[threadIdx.x] + 1));  // +1 self-loop
        }
    }
    for (int i = s0 + (int)threadIdx.x; i < s1; i += 256) {
        int p = bkt[i];
        int lo = (p >> 24) & 63;
        int li = atomicAdd(&cur[lo], 1);
        csr[s0 + bas[lo] + li] = p & 0xFFFFFF;
    }
}

// ---------------- graph boundaries from sorted batch ----------------

__global__ __launch_bounds__(256) void k_gbound(const int* __restrict__ batch,
                                                int* __restrict__ goff, int N, int G) {
    int i = blockIdx.x * 256 + threadIdx.x;
    if (i >= N) return;
    int b = batch[i];
    int prev = (i == 0) ? -1 : batch[i - 1];
    for (int g = prev + 1; g <= b; ++g) goff[g] = i;
    if (i == N - 1) {
        for (int g = b + 1; g <= G; ++g) goff[g] = N;
    }
}

// ---------------- skinny GEMM: Hh[N,64](fp16) = (relu? relu(X) : X) @ W ----------------
// fp32 accumulate, fp16 store (halves gather working set)

__global__ __launch_bounds__(256) void k_gemm(const float* __restrict__ X,
                                              const float* __restrict__ W,
                                              __half* __restrict__ Y, int N, int relu_in) {
    __shared__ float Ws[64 * 64];
    __shared__ float Xs[16 * 64];
    int tid = threadIdx.x;
#pragma unroll
    for (int i = 0; i < 16; ++i) Ws[tid + 256 * i] = W[tid + 256 * i];

    int row0 = blockIdx.x * 16;
    int r = tid >> 4, c4 = (tid & 15) << 2;
    {
        float4 v = make_float4(0.f, 0.f, 0.f, 0.f);
        if (row0 + r < N) v = *(const float4*)(X + (size_t)(row0 + r) * DIM + c4);
        if (relu_in) {
            v.x = fmaxf(v.x, 0.f); v.y = fmaxf(v.y, 0.f);
            v.z = fmaxf(v.z, 0.f); v.w = fmaxf(v.w, 0.f);
        }
        *(float4*)(Xs + r * DIM + c4) = v;
    }
    __syncthreads();

    float4 acc = make_float4(0.f, 0.f, 0.f, 0.f);
#pragma unroll
    for (int k = 0; k < 64; ++k) {
        float xk = Xs[r * DIM + k];
        float4 w = *(const float4*)(Ws + k * DIM + c4);
        acc.x += xk * w.x; acc.y += xk * w.y;
        acc.z += xk * w.z; acc.w += xk * w.w;
    }
    if (row0 + r < N) {
        __half2 p0 = __floats2half2_rn(acc.x, acc.y);
        __half2 p1 = __floats2half2_rn(acc.z, acc.w);
        uint2 u;
        u.x = *(unsigned int*)&p0;
        u.y = *(unsigned int*)&p1;
        *(uint2*)(Y + (size_t)(row0 + r) * DIM + c4) = u;
    }
}

// ---------------- gather: wave per node, fp16 rows, 4 edges per issue ----------------
// quarter q = lane>>4 handles one edge; 16 lanes * 4 halfs (8B) cover the 64-dim row.

__global__ __launch_bounds__(256) void k_gather(const __half* __restrict__ hH,
                                                const int* __restrict__ csr_src,
                                                const int* __restrict__ off,
                                                const float* __restrict__ dinv,
                                                const float* __restrict__ b,
                                                float* __restrict__ agg, int N) {
    int v = (blockIdx.x * 256 + threadIdx.x) >> 6;
    int lane = threadIdx.x & 63;
    if (v >= N) return;
    int q = lane >> 4, c = lane & 15;
    const uint2* h2 = (const uint2*)hH;   // 16 uint2 per 64-half row
    float dv = dinv[v];

    float4 acc = make_float4(0.f, 0.f, 0.f, 0.f);
    if (q == 0) {                          // self-loop + bias on quarter 0 only
        uint2 u = h2[(size_t)v * 16 + c];
        float2 f0 = __half22float2(*(__half2*)&u.x);
        float2 f1 = __half22float2(*(__half2*)&u.y);
        float4 bv = ((const float4*)b)[c];
        float n = dv * dv;
        acc = make_float4(f0.x * n + bv.x, f0.y * n + bv.y,
                          f1.x * n + bv.z, f1.y * n + bv.w);
    }

    int k0 = off[v], k1 = off[v + 1];
    for (int kb = k0; kb < k1; kb += 64) {
        int m = k1 - kb; if (m > 64) m = 64;
        int idx = 0; float wgt = 0.f;
        if (lane < m) {
            idx = csr_src[kb + lane];
            wgt = dinv[idx] * dv;
        }
        int mm = (m + 7) & ~7;
        for (int j = 0; j < mm; j += 8) {   // 8 edges per iter: 2 8B gathers/lane
            int   sA = __shfl(idx, j + q);
            float wA = __shfl(wgt, j + q);
            int   sB = __shfl(idx, j + 4 + q);
            float wB = __shfl(wgt, j + 4 + q);
            uint2 uA = h2[(size_t)sA * 16 + c];
            uint2 uB = h2[(size_t)sB * 16 + c];
            float2 a0 = __half22float2(*(__half2*)&uA.x);
            float2 a1 = __half22float2(*(__half2*)&uA.y);
            float2 b0 = __half22float2(*(__half2*)&uB.x);
            float2 b1 = __half22float2(*(__half2*)&uB.y);
            acc.x += a0.x * wA; acc.y += a0.y * wA;
            acc.z += a1.x * wA; acc.w += a1.y * wA;
            acc.x += b0.x * wB; acc.y += b0.y * wB;
            acc.z += b1.x * wB; acc.w += b1.y * wB;
        }
    }
    // reduce quarters: lanes (c, c+16, c+32, c+48) -> lane c
    acc.x += __shfl_down(acc.x, 32); acc.y += __shfl_down(acc.y, 32);
    acc.z += __shfl_down(acc.z, 32); acc.w += __shfl_down(acc.w, 32);
    acc.x += __shfl_down(acc.x, 16); acc.y += __shfl_down(acc.y, 16);
    acc.z += __shfl_down(acc.z, 16); acc.w += __shfl_down(acc.w, 16);
    if (q == 0) *(float4*)(agg + ((size_t)v << 6) + (c << 2)) = acc;
}

// ---------------- pool ----------------

__global__ __launch_bounds__(256) void k_pool(const float* __restrict__ agg,
                                              const int* __restrict__ goff,
                                              float* __restrict__ out, int G) {
    int g = blockIdx.x * 4 + (threadIdx.x >> 6);
    if (g >= G) return;
    int lane = threadIdx.x & 63;
    int q = lane >> 4, d4 = (lane & 15) << 2;
    int n0 = goff[g], n1 = goff[g + 1];
    float4 acc = make_float4(0.f, 0.f, 0.f, 0.f);
    for (int i = n0 + q; i < n1; i += 4) {
        float4 hv = *(const float4*)(agg + ((size_t)i << 6) + d4);
        acc.x += fmaxf(hv.x, 0.f); acc.y += fmaxf(hv.y, 0.f);
        acc.z += fmaxf(hv.z, 0.f); acc.w += fmaxf(hv.w, 0.f);
    }
    acc.x += __shfl_down(acc.x, 32); acc.y += __shfl_down(acc.y, 32);
    acc.z += __shfl_down(acc.z, 32); acc.w += __shfl_down(acc.w, 32);
    acc.x += __shfl_down(acc.x, 16); acc.y += __shfl_down(acc.y, 16);
    acc.z += __shfl_down(acc.z, 16); acc.w += __shfl_down(acc.w, 16);
    if (q == 0) {
        float inv = 1.0f / fmaxf((float)(n1 - n0), 1.0f);
        *(float4*)(out + ((size_t)g << 6) + d4) =
            make_float4(acc.x * inv, acc.y * inv, acc.z * inv, acc.w * inv);
    }
}

// ---------------- launch ----------------

static inline int cdiv(int a, int b) { return (a + b - 1) / b; }

extern "C" void kernel_launch(void* const* d_in, const int* in_sizes, int n_in,
                              void* d_out, int out_size, void* d_ws, size_t ws_size,
                              hipStream_t stream) {
    const float* x   = (const float*)d_in[0];
    const float* W1  = (const float*)d_in[1];
    const float* b1  = (const float*)d_in[2];
    const float* W2  = (const float*)d_in[3];
    const float* b2  = (const float*)d_in[4];
    const int*   ei  = (const int*)d_in[5];
    const int*   bat = (const int*)d_in[6];

    const int N = in_sizes[0] / DIM;
    const int E = in_sizes[5] / 2;
    const int G = out_size / DIM;
    const int NB = cdiv(N, 1 << BIN_SHIFT);   // <= MAXBINS
    const int M  = NB * PB;                   // scan length
    const int* src = ei;
    const int* dst = ei + E;
    float* out = (float*)d_out;

    // workspace: hH (fp16 N*64) | aggB (fp32 N*64) | dinv | off | goff | binoff | C | S | bsums | csr
    // bkt aliases hH (bucket/binsort finish before gemm writes hH).
    __half* hH    = (__half*)d_ws;                  // N*64 h (128B/row)
    float*  aggB  = (float*)(hH + (size_t)N * DIM); // N*64 f
    float*  dinv  = aggB + (size_t)N * DIM;         // N f
    int*    off   = (int*)(dinv + N);               // N+1 i
    int*    goff  = off + (N + 1);                  // G+1 i
    int*    binoff= goff + (G + 1);                 // NB+1 i
    int*    C     = binoff + (NB + 1);              // PB*NB i
    int*    S     = C + (size_t)PB * NB;            // PB*NB i
    int*    bsums = S + (size_t)PB * NB;            // up to 1024 i
    int*    csr   = bsums + 1024;                   // E i
    int*    bkt   = (int*)hH;                       // E i (aliased)

    k_hist<<<PB, 256, 0, stream>>>(dst, C, E, NB);
    int nb2 = cdiv(M, 4096);
    k_scanA<<<nb2, 1024, 0, stream>>>(C, S, bsums, NB, M);
    k_scanB<<<1, 1024, 0, stream>>>(bsums, nb2);
    k_scanC<<<nb2, 1024, 0, stream>>>(S, bsums, binoff, off + N, NB, M, E);
    k_bucket<<<PB, 256, 0, stream>>>(src, dst, S, bkt, E, NB);
    k_binsort<<<NB, 256, 0, stream>>>(bkt, binoff, csr, off, dinv, N);
    k_gbound<<<cdiv(N, 256), 256, 0, stream>>>(bat, goff, N, G);

    k_gemm<<<cdiv(N, 16), 256, 0, stream>>>(x, W1, hH, N, 0);
    k_gather<<<cdiv(N, 4), 256, 0, stream>>>(hH, csr, off, dinv, b1, aggB, N);

    k_gemm<<<cdiv(N, 16), 256, 0, stream>>>(aggB, W2, hH, N, 1);
    k_gather<<<cdiv(N, 4), 256, 0, stream>>>(hH, csr, off, dinv, b2, aggB, N);

    k_pool<<<cdiv(G, 4), 256, 0, stream>>>(aggB, goff, out, G);
}

// Round 10
// 279.390 us; speedup vs baseline: 11.0574x; 1.0213x over previous
//
#include <hip/hip_runtime.h>
#include <hip/hip_fp16.h>

#define DIM 64
#define BIN_SHIFT 8
#define BINSZ 256      // nodes per bin
#define MAXBINS 512    // supports N up to 131072
#define PB 256         // edge-slice blocks for hist/bucket (power of 2)
#define PB_LOG 8

// ---------------- pass 1: per-block LDS histogram -> C[blk][bin] (coalesced) ----------------

__global__ __launch_bounds__(256) void k_hist(const int* __restrict__ dst,
                                              int* __restrict__ C, int E, int NB) {
    __shared__ int h[MAXBINS];
    for (int i = threadIdx.x; i < NB; i += 256) h[i] = 0;
    __syncthreads();
    int per = (E + PB - 1) / PB;
    int e0 = blockIdx.x * per;
    int e1 = e0 + per; if (e1 > E) e1 = E;
    for (int e = e0 + (int)threadIdx.x; e < e1; e += 256)
        atomicAdd(&h[dst[e] >> BIN_SHIFT], 1);
    __syncthreads();
    for (int i = threadIdx.x; i < NB; i += 256)
        C[blockIdx.x * NB + i] = h[i];
}

// ---------------- pass 2: exclusive scan of C in bin-major logical order ----------------
// logical j: bin = j>>PB_LOG, blk = j&(PB-1); S[j] = global start of run (bin,blk)

__global__ __launch_bounds__(1024) void k_scanA(const int* __restrict__ C,
                                                int* __restrict__ S,
                                                int* __restrict__ bsums, int NB, int M) {
    __shared__ int sh[1024];
    int tid = threadIdx.x;
    int j0 = blockIdx.x * 4096 + tid * 4;
    int v[4]; int sum = 0;
#pragma unroll
    for (int t = 0; t < 4; ++t) {
        int j = j0 + t; int x = 0;
        if (j < M) { int bin = j >> PB_LOG, blk = j & (PB - 1); x = C[blk * NB + bin]; }
        v[t] = sum; sum += x;
    }
    sh[tid] = sum;
    __syncthreads();
#pragma unroll
    for (int d = 1; d < 1024; d <<= 1) {
        int t = (tid >= d) ? sh[tid - d] : 0;
        __syncthreads();
        sh[tid] += t;
        __syncthreads();
    }
    int excl = sh[tid] - sum;
#pragma unroll
    for (int t = 0; t < 4; ++t) {
        int j = j0 + t;
        if (j < M) S[j] = excl + v[t];
    }
    if (tid == 1023) bsums[blockIdx.x] = sh[1023];
}

__global__ __launch_bounds__(1024) void k_scanB(int* __restrict__ bsums, int nb) {
    __shared__ int s[1024];
    int tid = threadIdx.x;
    int v = (tid < nb) ? bsums[tid] : 0;
    s[tid] = v;
    __syncthreads();
#pragma unroll
    for (int d = 1; d < 1024; d <<= 1) {
        int t = (tid >= d) ? s[tid - d] : 0;
        __syncthreads();
        s[tid] += t;
        __syncthreads();
    }
    if (tid < nb) bsums[tid] = s[tid] - v;
}

__global__ __launch_bounds__(1024) void k_scanC(int* __restrict__ S,
                                                const int* __restrict__ bsums,
                                                int* __restrict__ binoff,
                                                int* __restrict__ offN,
                                                int NB, int M, int E) {
    int tid = threadIdx.x;
    int j0 = blockIdx.x * 4096 + tid * 4;
    int add = bsums[blockIdx.x];
#pragma unroll
    for (int t = 0; t < 4; ++t) {
        int j = j0 + t;
        if (j < M) {
            int val = S[j] + add;
            S[j] = val;
            if ((j & (PB - 1)) == 0) binoff[j >> PB_LOG] = val;
        }
    }
    if (blockIdx.x == 0 && tid == 0) { binoff[NB] = E; offN[0] = E; }
}

// ---------------- pass 3: one-pass bucket scatter, LDS cursors, no global atomics ----------------
// ~16-edge runs per (bin,blk) -> mostly full-line bkt writes

__global__ __launch_bounds__(256) void k_bucket(const int* __restrict__ src,
                                                const int* __restrict__ dst,
                                                const int* __restrict__ S,
                                                int* __restrict__ bkt, int E, int NB) {
    __shared__ int lcur[MAXBINS];
    int blk = blockIdx.x;
    for (int i = threadIdx.x; i < NB; i += 256)
        lcur[i] = S[i * PB + blk];
    __syncthreads();
    int per = (E + PB - 1) / PB;
    int e0 = blk * per;
    int e1 = e0 + per; if (e1 > E) e1 = E;
    for (int e = e0 + (int)threadIdx.x; e < e1; e += 256) {
        int d = dst[e];
        int pos = atomicAdd(&lcur[d >> BIN_SHIFT], 1);
        bkt[pos] = src[e] | ((d & (BINSZ - 1)) << 24);
    }
}

// ---------------- pass 4: per-bin 256-way counting sort -> csr, off, dinv ----------------

__global__ __launch_bounds__(256) void k_binsort(const int* __restrict__ bkt,
                                                 const int* __restrict__ binoff,
                                                 int* __restrict__ csr,
                                                 int* __restrict__ off,
                                                 float* __restrict__ dinv, int N) {
    __shared__ int cnt[BINSZ], bas[BINSZ], cur[BINSZ];
    int tid = threadIdx.x;
    int b = blockIdx.x;
    int s0 = binoff[b], s1 = binoff[b + 1];
    cnt[tid] = 0; cur[tid] = 0;
    __syncthreads();
    for (int i = s0 + tid; i < s1; i += 256)
        atomicAdd(&cnt[(bkt[i] >> 24) & 255], 1);
    __syncthreads();
    int my = cnt[tid];
    bas[tid] = my;
    __syncthreads();
#pragma unroll
    for (int d = 1; d < 256; d <<= 1) {
        int t = (tid >= d) ? bas[tid - d] : 0;
        __syncthreads();
        bas[tid] += t;
        __syncthreads();
    }
    int ex = bas[tid] - my;
    __syncthreads();
    bas[tid] = ex;                       // exclusive base within bin
    {
        int v = (b << BIN_SHIFT) + tid;
        if (v < N) {
            off[v] = s0 + ex;
            dinv[v] = rsqrtf((float)(my + 1));   // +1 self-loop
        }
    }
    __syncthreads();
    for (int i = s0 + tid; i < s1; i += 256) {
        int p = bkt[i];
        int lo = (p >> 24) & 255;
        int li = atomicAdd(&cur[lo], 1);
        csr[s0 + bas[lo] + li] = p & 0xFFFFFF;
    }
}

// ---------------- graph boundaries from sorted batch ----------------

__global__ __launch_bounds__(256) void k_gbound(const int* __restrict__ batch,
                                                int* __restrict__ goff, int N, int G) {
    int i = blockIdx.x * 256 + threadIdx.x;
    if (i >= N) return;
    int b = batch[i];
    int prev = (i == 0) ? -1 : batch[i - 1];
    for (int g = prev + 1; g <= b; ++g) goff[g] = i;
    if (i == N - 1) {
        for (int g = b + 1; g <= G; ++g) goff[g] = N;
    }
}

// ---------------- skinny GEMM: hs[N,64](fp16) = ((relu? relu(X):X) @ W) * dinv[row] ----------------
// fp32 accumulate; row N (zero row) written as zeros for gather lane padding

__global__ __launch_bounds__(256) void k_gemm(const float* __restrict__ X,
                                              const float* __restrict__ W,
                                              const float* __restrict__ dinv,
                                              __half* __restrict__ Y, int N, int relu_in) {
    __shared__ float Ws[64 * 64];
    __shared__ float Xs[16 * 64];
    int tid = threadIdx.x;
#pragma unroll
    for (int i = 0; i < 16; ++i) Ws[tid + 256 * i] = W[tid + 256 * i];

    int row0 = blockIdx.x * 16;
    int r = tid >> 4, c4 = (tid & 15) << 2;
    int row = row0 + r;
    {
        float4 v = make_float4(0.f, 0.f, 0.f, 0.f);
        if (row < N) v = *(const float4*)(X + (size_t)row * DIM + c4);
        if (relu_in) {
            v.x = fmaxf(v.x, 0.f); v.y = fmaxf(v.y, 0.f);
            v.z = fmaxf(v.z, 0.f); v.w = fmaxf(v.w, 0.f);
        }
        *(float4*)(Xs + r * DIM + c4) = v;
    }
    __syncthreads();

    float4 acc = make_float4(0.f, 0.f, 0.f, 0.f);
#pragma unroll
    for (int k = 0; k < 64; ++k) {
        float xk = Xs[r * DIM + k];
        float4 w = *(const float4*)(Ws + k * DIM + c4);
        acc.x += xk * w.x; acc.y += xk * w.y;
        acc.z += xk * w.z; acc.w += xk * w.w;
    }
    if (row < N) {
        float s = dinv[row];
        __half2 p0 = __floats2half2_rn(acc.x * s, acc.y * s);
        __half2 p1 = __floats2half2_rn(acc.z * s, acc.w * s);
        uint2 u;
        u.x = *(unsigned int*)&p0;
        u.y = *(unsigned int*)&p1;
        *(uint2*)(Y + (size_t)row * DIM + c4) = u;
    } else if (row == N) {               // zero row for padded gather lanes
        uint2 z; z.x = 0u; z.y = 0u;
        *(uint2*)(Y + (size_t)row * DIM + c4) = z;
    }
}

// ---------------- gather: agg[v] = dv*(hs[v] + sum hs[nbr]) + b ; plain row-sum ----------------

__global__ __launch_bounds__(256) void k_gather(const __half* __restrict__ hs,
                                                const int* __restrict__ csr_src,
                                                const int* __restrict__ off,
                                                const float* __restrict__ dinv,
                                                const float* __restrict__ b,
                                                float* __restrict__ agg, int N) {
    int v = (blockIdx.x * 256 + threadIdx.x) >> 6;
    int lane = threadIdx.x & 63;
    if (v >= N) return;
    int q = lane >> 4, c = lane & 15;
    const uint2* h2 = (const uint2*)hs;   // 16 uint2 per 64-half row

    float4 acc = make_float4(0.f, 0.f, 0.f, 0.f);
    if (q == 0) {                          // self-loop term hs[v]
        uint2 u = h2[(size_t)v * 16 + c];
        float2 f0 = __half22float2(*(__half2*)&u.x);
        float2 f1 = __half22float2(*(__half2*)&u.y);
        acc = make_float4(f0.x, f0.y, f1.x, f1.y);
    }

    int k0 = off[v], k1 = off[v + 1];
    for (int kb = k0; kb < k1; kb += 64) {
        int m = k1 - kb;
        int idx = N;                       // zero row for padding lanes
        if (lane < m) idx = csr_src[kb + lane];
        int mlim = m > 64 ? 64 : m;
        int mm = (mlim + 7) & ~7;
        for (int j = 0; j < mm; j += 8) {  // 8 edges per iter: 2 8B gathers/lane
            int sA = __shfl(idx, j + q);
            int sB = __shfl(idx, j + 4 + q);
            uint2 uA = h2[(size_t)sA * 16 + c];
            uint2 uB = h2[(size_t)sB * 16 + c];
            float2 a0 = __half22float2(*(__half2*)&uA.x);
            float2 a1 = __half22float2(*(__half2*)&uA.y);
            float2 b0 = __half22float2(*(__half2*)&uB.x);
            float2 b1 = __half22float2(*(__half2*)&uB.y);
            acc.x += a0.x + b0.x; acc.y += a0.y + b0.y;
            acc.z += a1.x + b1.x; acc.w += a1.y + b1.y;
        }
    }
    // reduce quarters: lanes (c, c+16, c+32, c+48) -> lane c
    acc.x += __shfl_down(acc.x, 32); acc.y += __shfl_down(acc.y, 32);
    acc.z += __shfl_down(acc.z, 32); acc.w += __shfl_down(acc.w, 32);
    acc.x += __shfl_down(acc.x, 16); acc.y += __shfl_down(acc.y, 16);
    acc.z += __shfl_down(acc.z, 16); acc.w += __shfl_down(acc.w, 16);
    if (q == 0) {
        float dv = dinv[v];
        float4 bv = ((const float4*)b)[c];
        *(float4*)(agg + ((size_t)v << 6) + (c << 2)) =
            make_float4(acc.x * dv + bv.x, acc.y * dv + bv.y,
                        acc.z * dv + bv.z, acc.w * dv + bv.w);
    }
}

// ---------------- pool ----------------

__global__ __launch_bounds__(256) void k_pool(const float* __restrict__ agg,
                                              const int* __restrict__ goff,
                                              float* __restrict__ out, int G) {
    int g = blockIdx.x * 4 + (threadIdx.x >> 6);
    if (g >= G) return;
    int lane = threadIdx.x & 63;
    int q = lane >> 4, d4 = (lane & 15) << 2;
    int n0 = goff[g], n1 = goff[g + 1];
    float4 acc = make_float4(0.f, 0.f, 0.f, 0.f);
    for (int i = n0 + q; i < n1; i += 4) {
        float4 hv = *(const float4*)(agg + ((size_t)i << 6) + d4);
        acc.x += fmaxf(hv.x, 0.f); acc.y += fmaxf(hv.y, 0.f);
        acc.z += fmaxf(hv.z, 0.f); acc.w += fmaxf(hv.w, 0.f);
    }
    acc.x += __shfl_down(acc.x, 32); acc.y += __shfl_down(acc.y, 32);
    acc.z += __shfl_down(acc.z, 32); acc.w += __shfl_down(acc.w, 32);
    acc.x += __shfl_down(acc.x, 16); acc.y += __shfl_down(acc.y, 16);
    acc.z += __shfl_down(acc.z, 16); acc.w += __shfl_down(acc.w, 16);
    if (q == 0) {
        float inv = 1.0f / fmaxf((float)(n1 - n0), 1.0f);
        *(float4*)(out + ((size_t)g << 6) + d4) =
            make_float4(acc.x * inv, acc.y * inv, acc.z * inv, acc.w * inv);
    }
}

// ---------------- launch ----------------

static inline int cdiv(int a, int b) { return (a + b - 1) / b; }

extern "C" void kernel_launch(void* const* d_in, const int* in_sizes, int n_in,
                              void* d_out, int out_size, void* d_ws, size_t ws_size,
                              hipStream_t stream) {
    const float* x   = (const float*)d_in[0];
    const float* W1  = (const float*)d_in[1];
    const float* b1  = (const float*)d_in[2];
    const float* W2  = (const float*)d_in[3];
    const float* b2  = (const float*)d_in[4];
    const int*   ei  = (const int*)d_in[5];
    const int*   bat = (const int*)d_in[6];

    const int N = in_sizes[0] / DIM;
    const int E = in_sizes[5] / 2;
    const int G = out_size / DIM;
    const int NB = cdiv(N, BINSZ);           // <= MAXBINS
    const int M  = NB * PB;                  // scan length
    const int* src = ei;
    const int* dst = ei + E;
    float* out = (float*)d_out;

    // workspace: hs(fp16 (N+1)*64) | aggB(fp32 N*64) | dinv | off | goff | binoff | C | S | bsums | csr
    // bkt aliases hs (bucket/binsort finish before gemm writes hs).
    __half* hs     = (__half*)d_ws;                    // (N+1)*64 h
    float*  aggB   = (float*)(hs + (size_t)(N + 1) * DIM); // N*64 f
    float*  dinv   = aggB + (size_t)N * DIM;           // N f
    int*    off    = (int*)(dinv + N);                 // N+1 i
    int*    goff   = off + (N + 1);                    // G+1 i
    int*    binoff = goff + (G + 1);                   // NB+1 i
    int*    C      = binoff + (NB + 1);                // PB*NB i
    int*    S      = C + (size_t)PB * NB;              // PB*NB i
    int*    bsums  = S + (size_t)PB * NB;              // up to 1024 i
    int*    csr    = bsums + 1024;                     // E i
    int*    bkt    = (int*)hs;                         // E i (aliased)

    k_hist<<<PB, 256, 0, stream>>>(dst, C, E, NB);
    int nb2 = cdiv(M, 4096);
    k_scanA<<<nb2, 1024, 0, stream>>>(C, S, bsums, NB, M);
    k_scanB<<<1, 1024, 0, stream>>>(bsums, nb2);
    k_scanC<<<nb2, 1024, 0, stream>>>(S, bsums, binoff, off + N, NB, M, E);
    k_bucket<<<PB, 256, 0, stream>>>(src, dst, S, bkt, E, NB);
    k_binsort<<<NB, 256, 0, stream>>>(bkt, binoff, csr, off, dinv, N);
    k_gbound<<<cdiv(N, 256), 256, 0, stream>>>(bat, goff, N, G);

    k_gemm<<<cdiv(N + 1, 16), 256, 0, stream>>>(x, W1, dinv, hs, N, 0);
    k_gather<<<cdiv(N, 4), 256, 0, stream>>>(hs, csr, off, dinv, b1, aggB, N);

    k_gemm<<<cdiv(N + 1, 16), 256, 0, stream>>>(aggB, W2, dinv, hs, N, 1);
    k_gather<<<cdiv(N, 4), 256, 0, stream>>>(hs, csr, off, dinv, b2, aggB, N);

    k_pool<<<cdiv(G, 4), 256, 0, stream>>>(aggB, goff, out, G);
}